// Round 1
// baseline (1031.400 us; speedup 1.0000x reference)
//
#include <hip/hip_runtime.h>
#include <math.h>

// ---------------- conv1: 1x1 stride2, 3->16 ----------------
__global__ __launch_bounds__(256) void k_conv1(const float* __restrict__ x,
    const float* __restrict__ w, const float* __restrict__ b, float* __restrict__ y) {
  int t = blockIdx.x*256 + threadIdx.x;        // 16*128*128 pixels
  int ox = t & 127, oy = (t >> 7) & 127, bb = t >> 14;
  const float* xp = x + ((size_t)((bb*256 + 2*oy)*256 + 2*ox))*3;
  float x0 = xp[0], x1 = xp[1], x2 = xp[2];
  float* yp = y + (size_t)t*16;
  #pragma unroll
  for (int c = 0; c < 16; ++c)
    yp[c] = b[c] + x0*w[c] + x1*w[16+c] + x2*w[32+c];
}

// ---------------- generic 3x3 stride-2 SAME conv (pad_beg=0) ----------------
template<int CIN,int COUT,int G,int HIN,int HOUT>
__global__ __launch_bounds__(256) void k_conv(const float* __restrict__ h,
    const float* __restrict__ w, const float* __restrict__ bias, float* __restrict__ y) {
  const int NGRP = COUT/G;
  int t = blockIdx.x*256 + threadIdx.x;
  int grp = t % NGRP;
  int px  = t / NGRP;
  int ox = px % HOUT, oy = (px/HOUT) % HOUT, bb = px/(HOUT*HOUT);
  float acc[G];
  #pragma unroll
  for (int j=0;j<G;++j) acc[j] = bias[grp*G+j];
  #pragma unroll
  for (int dy=0; dy<3; ++dy) {
    int iy = 2*oy + dy;
    if (iy >= HIN) continue;
    #pragma unroll
    for (int dx=0; dx<3; ++dx) {
      int ix = 2*ox + dx;
      if (ix >= HIN) continue;
      const float* hp = h + ((size_t)(bb*HIN + iy)*HIN + ix)*CIN;
      const float* wp = w + ((size_t)(dy*3+dx)*CIN)*COUT + grp*G;
      #pragma unroll
      for (int ci=0; ci<CIN; ++ci) {
        float v = hp[ci];
        #pragma unroll
        for (int j=0;j<G;++j) acc[j] = fmaf(v, wp[ci*COUT + j], acc[j]);
      }
    }
  }
  float* yp = y + (size_t)px*COUT + grp*G;
  #pragma unroll
  for (int j=0;j<G;++j) yp[j] = acc[j];
}

// ---------------- BN batch-stats partials (deterministic, no atomics) ----------------
template<int C>
__global__ __launch_bounds__(256) void k_stats(const float* __restrict__ y, int nelem,
                                               float* __restrict__ partials) {
  int tid = threadIdx.x;
  int T = gridDim.x*256;
  float s = 0.f, q = 0.f;
  for (int e = blockIdx.x*256 + tid; e < nelem; e += T) {
    float v = y[e];
    s += v; q = fmaf(v, v, q);
  }
  // lane holds channel (lane % C); fold lanes with same channel
  #pragma unroll
  for (int off = C; off < 64; off <<= 1) {
    s += __shfl_xor(s, off);
    q += __shfl_xor(q, off);
  }
  __shared__ float lw[4][2*C];
  int wv = tid >> 6, lane = tid & 63;
  if (lane < C) { lw[wv][lane] = s; lw[wv][C+lane] = q; }
  __syncthreads();
  if (tid < 2*C)
    partials[(size_t)blockIdx.x*2*C + tid] = lw[0][tid]+lw[1][tid]+lw[2][tid]+lw[3][tid];
}

// ---------------- finalize: mean/var -> scale/shift ----------------
template<int C>
__global__ __launch_bounds__(256) void k_finalize(const float* __restrict__ partials, int nblk,
    double inv_n, const float* __restrict__ g, const float* __restrict__ be, float* __restrict__ ss) {
  const int NSTAT = 2*C;
  const int PER = 256/NSTAT;
  __shared__ double red[256];
  int tid = threadIdx.x;
  int stat = tid % NSTAT, sub = tid / NSTAT;
  double acc = 0.0;
  for (int i = sub; i < nblk; i += PER) acc += (double)partials[(size_t)i*NSTAT + stat];
  red[tid] = acc;
  __syncthreads();
  for (int off = PER>>1; off > 0; off >>= 1) {
    if (sub < off) red[tid] += red[tid + off*NSTAT];
    __syncthreads();
  }
  if (tid < C) {
    double mean = red[tid]*inv_n;
    double var  = red[C+tid]*inv_n - mean*mean;
    float scale = g[tid] * rsqrtf((float)var + 1e-3f);
    float shift = be[tid] - (float)mean*scale;
    ss[tid] = scale; ss[C+tid] = shift;
  }
}

// ---------------- BN apply + ReLU ----------------
template<int C>
__global__ __launch_bounds__(256) void k_bnrelu(const float* __restrict__ y,
    const float* __restrict__ ss, float* __restrict__ h, int n4) {
  int t = blockIdx.x*256 + threadIdx.x;
  if (t >= n4) return;
  float4 v = ((const float4*)y)[t];
  int c = (t*4) % C;
  float4 r;
  r.x = fmaxf(0.f, fmaf(v.x, ss[c+0], ss[C+c+0]));
  r.y = fmaxf(0.f, fmaf(v.y, ss[c+1], ss[C+c+1]));
  r.z = fmaxf(0.f, fmaf(v.z, ss[c+2], ss[C+c+2]));
  r.w = fmaxf(0.f, fmaf(v.w, ss[c+3], ss[C+c+3]));
  ((float4*)h)[t] = r;
}

// ---------------- memory module: scores + fused online softmax partials ----------------
// s[p][n] = (z.mem + 1e-12)/(sum((z*mem)^2) + 1e-12); scoresT layout [n][p]
__global__ __launch_bounds__(256) void k_scores(const float* __restrict__ z,
    const float* __restrict__ mem, float* __restrict__ scoresT,
    float* __restrict__ partM, float* __restrict__ partS) {
  int pb = blockIdx.x & 63;       // 64 position blocks (16384/256)
  int nc = blockIdx.x >> 6;       // 10 n-chunks of 200
  int p  = (pb << 8) + threadIdx.x;
  float4 zv[16];
  const float4* zp = (const float4*)(z + (size_t)p*64);
  #pragma unroll
  for (int i=0;i<16;++i) zv[i] = zp[i];
  float m = -3.4e38f, S = 0.f;
  int n0 = nc*200;
  for (int nn = n0; nn < n0+200; ++nn) {
    const float4* mp = (const float4*)(mem + (size_t)nn*64);  // uniform -> scalar loads
    float num = 1e-12f, den = 1e-12f;
    #pragma unroll
    for (int i=0;i<16;++i) {
      float4 m4 = mp[i], z4 = zv[i];
      float t0 = z4.x*m4.x; num += t0; den = fmaf(t0,t0,den);
      float t1 = z4.y*m4.y; num += t1; den = fmaf(t1,t1,den);
      float t2 = z4.z*m4.z; num += t2; den = fmaf(t2,t2,den);
      float t3 = z4.w*m4.w; num += t3; den = fmaf(t3,t3,den);
    }
    float s = num/den;
    scoresT[(size_t)nn*16384 + p] = s;
    float mn = fmaxf(m, s);
    S = S*__expf(m - mn) + __expf(s - mn);
    m = mn;
  }
  partM[(size_t)nc*16384 + p] = m;
  partS[(size_t)nc*16384 + p] = S;
}

__global__ __launch_bounds__(256) void k_smcomb(const float* __restrict__ partM,
    const float* __restrict__ partS, float* __restrict__ M, float* __restrict__ IS) {
  int p = blockIdx.x*256 + threadIdx.x;
  float m = -3.4e38f;
  #pragma unroll
  for (int c=0;c<10;++c) m = fmaxf(m, partM[(size_t)c*16384+p]);
  float S = 0.f;
  #pragma unroll
  for (int c=0;c<10;++c) S += partS[(size_t)c*16384+p]*__expf(partM[(size_t)c*16384+p]-m);
  M[p] = m;
  IS[p] = 1.f/S;
}

// ---------------- z_hat = shrink(softmax(scores)) @ mem ----------------
__global__ __launch_bounds__(256) void k_zhat(const float* __restrict__ scoresT,
    const float* __restrict__ mem, const float* __restrict__ M, const float* __restrict__ IS,
    float* __restrict__ zhat) {
  __shared__ float4 mlds4[64*16];          // 64 mem rows x 64 ch
  __shared__ float rlds[64*33];            // renorm [n][p], padded
  float* mlds = (float*)mlds4;
  int p0 = blockIdx.x*32;
  int tid = threadIdx.x;
  int pl = tid >> 3, cg = tid & 7;         // GEMM mapping: 32 pos x 8 ch-groups
  int lp = tid & 31, ln = tid >> 5;        // loader mapping: 32 pos x 8 rows
  float mreg = M[p0 + lp], isreg = IS[p0 + lp];
  float acc[8];
  #pragma unroll
  for (int i=0;i<8;++i) acc[i]=0.f;
  for (int t=0; t<32; ++t) {
    int nt0 = t*64;
    int nvalid = 2000 - nt0; if (nvalid > 64) nvalid = 64;
    __syncthreads();
    for (int i=tid; i<nvalid*16; i+=256) mlds4[i] = ((const float4*)mem)[nt0*16 + i];
    #pragma unroll
    for (int it=0; it<8; ++it) {
      int nl = ln + it*8;
      float r = 0.f;
      if (nl < nvalid) {
        float s = scoresT[(size_t)(nt0+nl)*16384 + p0 + lp];
        float att = __expf(s - mreg)*isreg;
        float d = att - 0.0005f;
        float rel = fmaxf(d, 0.f)*att/(fabsf(d)+1e-12f);
        r = fminf(fmaxf(rel, 1e-12f), 1.0f);
      }
      rlds[nl*33 + lp] = r;
    }
    __syncthreads();
    for (int nn=0; nn<nvalid; ++nn) {
      float r = rlds[nn*33 + pl];
      float4 a = mlds4[nn*16 + cg*2];
      float4 b = mlds4[nn*16 + cg*2 + 1];
      acc[0] = fmaf(r, a.x, acc[0]); acc[1] = fmaf(r, a.y, acc[1]);
      acc[2] = fmaf(r, a.z, acc[2]); acc[3] = fmaf(r, a.w, acc[3]);
      acc[4] = fmaf(r, b.x, acc[4]); acc[5] = fmaf(r, b.y, acc[5]);
      acc[6] = fmaf(r, b.z, acc[6]); acc[7] = fmaf(r, b.w, acc[7]);
    }
  }
  float* zp = zhat + (size_t)(p0+pl)*64 + cg*8;
  #pragma unroll
  for (int i=0;i<8;++i) zp[i] = acc[i];
}

// ---------------- conv_transpose 3x3 stride2 SAME (adjoint of fwd conv, pad_beg=0) ----------------
// w layout [ki][kj][COUT][CIN]; out[m] taps: (m-ki) even, i=(m-ki)/2 in [0,HIN)
template<int CIN,int COUT,int G,int HIN>
__global__ __launch_bounds__(256) void k_convt(const float* __restrict__ zin,
    const float* __restrict__ w, const float* __restrict__ bias, float* __restrict__ y) {
  const int NGRP = COUT/G;
  const int HOUT = HIN*2;
  int t = blockIdx.x*256 + threadIdx.x;
  int grp = t % NGRP;
  int px  = t / NGRP;
  int n = px % HOUT, m = (px/HOUT) % HOUT, bb = px/(HOUT*HOUT);
  float acc[G];
  #pragma unroll
  for (int j=0;j<G;++j) acc[j] = bias[grp*G+j];
  for (int ki=0; ki<3; ++ki) {
    int mi = m - ki;
    if (mi & 1) continue;
    int i = mi >> 1;
    if (i < 0 || i >= HIN) continue;
    for (int kj=0; kj<3; ++kj) {
      int nj = n - kj;
      if (nj & 1) continue;
      int j2 = nj >> 1;
      if (j2 < 0 || j2 >= HIN) continue;
      const float* zp = zin + ((size_t)(bb*HIN + i)*HIN + j2)*CIN;
      float v[CIN];
      #pragma unroll
      for (int ci=0;ci<CIN;++ci) v[ci] = zp[ci];
      const float* wp = w + ((size_t)(ki*3+kj)*COUT + grp*G)*CIN;
      #pragma unroll
      for (int j=0;j<G;++j) {
        #pragma unroll
        for (int ci=0;ci<CIN;++ci)
          acc[j] = fmaf(v[ci], wp[j*CIN + ci], acc[j]);
      }
    }
  }
  float* yp = y + (size_t)px*COUT + grp*G;
  #pragma unroll
  for (int j=0;j<G;++j) yp[j] = acc[j];
}

// ---------------- final conv_transpose 16->3 + clip, writes d_out ----------------
__global__ __launch_bounds__(256) void k_convt_final(const float* __restrict__ zin,
    const float* __restrict__ w, const float* __restrict__ bias, float* __restrict__ out) {
  const int CIN=16, HIN=128, HOUT=256;
  int px = blockIdx.x*256 + threadIdx.x;   // 16*256*256
  int n = px % HOUT, m = (px/HOUT) % HOUT, bb = px/(HOUT*HOUT);
  float a0 = bias[0], a1 = bias[1], a2 = bias[2];
  for (int ki=0; ki<3; ++ki) {
    int mi = m - ki; if (mi & 1) continue; int i = mi >> 1; if (i < 0 || i >= HIN) continue;
    for (int kj=0; kj<3; ++kj) {
      int nj = n - kj; if (nj & 1) continue; int j2 = nj >> 1; if (j2 < 0 || j2 >= HIN) continue;
      const float* zp = zin + ((size_t)(bb*HIN + i)*HIN + j2)*CIN;
      const float* wp = w + (size_t)(ki*3+kj)*3*CIN;
      #pragma unroll
      for (int ci=0;ci<CIN;++ci) {
        float v = zp[ci];
        a0 = fmaf(v, wp[ci],       a0);
        a1 = fmaf(v, wp[CIN+ci],   a1);
        a2 = fmaf(v, wp[2*CIN+ci], a2);
      }
    }
  }
  float* op = out + (size_t)px*3;
  op[0] = fminf(fmaxf(a0, 1e-12f), 1.0f);
  op[1] = fminf(fmaxf(a1, 1e-12f), 1.0f);
  op[2] = fminf(fmaxf(a2, 1e-12f), 1.0f);
}

extern "C" void kernel_launch(void* const* d_in, const int* in_sizes, int n_in,
                              void* d_out, int out_size, void* d_ws, size_t ws_size,
                              hipStream_t stream) {
  const float* x    = (const float*)d_in[0];
  const float* w_e1 = (const float*)d_in[1];
  const float* b_e1 = (const float*)d_in[2];
  const float* g1   = (const float*)d_in[3];
  const float* be1  = (const float*)d_in[4];
  const float* w_e2 = (const float*)d_in[5];
  const float* b_e2 = (const float*)d_in[6];
  const float* g2   = (const float*)d_in[7];
  const float* be2  = (const float*)d_in[8];
  const float* w_e3 = (const float*)d_in[9];
  const float* b_e3 = (const float*)d_in[10];
  const float* g3   = (const float*)d_in[11];
  const float* be3  = (const float*)d_in[12];
  const float* wmem = (const float*)d_in[13];
  const float* w_d1 = (const float*)d_in[14];
  const float* b_d1 = (const float*)d_in[15];
  const float* gt1  = (const float*)d_in[16];
  const float* bet1 = (const float*)d_in[17];
  const float* w_d2 = (const float*)d_in[18];
  const float* b_d2 = (const float*)d_in[19];
  const float* gt2  = (const float*)d_in[20];
  const float* bet2 = (const float*)d_in[21];
  const float* w_d3 = (const float*)d_in[22];
  const float* b_d3 = (const float*)d_in[23];
  float* out = (float*)d_out;

  float* ws = (float*)d_ws;
  float* A  = ws;                    // 4194304  y1 / t2p
  float* Bh = A  + 4194304;          // 4194304  h1 / t2
  float* Cc = Bh + 4194304;          // 2097152  y2 / t1p
  float* D  = Cc + 2097152;          // 2097152  h2 / t1
  float* E  = D  + 2097152;          // 1048576  y3
  float* F  = E  + 1048576;          // 1048576  z
  float* Gz = F  + 1048576;          // 1048576  zhat
  float* S  = Gz + 1048576;          // 32768000 scoresT [2000][16384]
  float* PT = S  + 32768000;         // 131072   BN partials (reused)
  float* SS = PT + 131072;           // 256      scale/shift (reused)
  float* PM = SS + 256;              // 163840   softmax partial max
  float* PS = PM + 163840;           // 163840   softmax partial sumexp
  float* MM = PS + 163840;           // 16384
  float* IS = MM + 16384;            // 16384
  (void)ws_size; (void)in_sizes; (void)n_in; (void)out_size;

  // ---- encoder ----
  k_conv1<<<1024,256,0,stream>>>(x, w_e1, b_e1, A);
  k_stats<16><<<512,256,0,stream>>>(A, 4194304, PT);
  k_finalize<16><<<1,256,0,stream>>>(PT, 512, 1.0/262144.0, g1, be1, SS);
  k_bnrelu<16><<<4096,256,0,stream>>>(A, SS, Bh, 1048576);
  k_conv<16,32,16,128,64><<<512,256,0,stream>>>(Bh, w_e2, b_e2, Cc);
  k_stats<32><<<512,256,0,stream>>>(Cc, 2097152, PT);
  k_finalize<32><<<1,256,0,stream>>>(PT, 512, 1.0/65536.0, g2, be2, SS);
  k_bnrelu<32><<<2048,256,0,stream>>>(Cc, SS, D, 524288);
  k_conv<32,64,8,64,32><<<512,256,0,stream>>>(D, w_e3, b_e3, E);
  k_stats<64><<<512,256,0,stream>>>(E, 1048576, PT);
  k_finalize<64><<<1,256,0,stream>>>(PT, 512, 1.0/16384.0, g3, be3, SS);
  k_bnrelu<64><<<1024,256,0,stream>>>(E, SS, F, 262144);
  // ---- memory addressing ----
  k_scores<<<640,256,0,stream>>>(F, wmem, S, PM, PS);
  k_smcomb<<<64,256,0,stream>>>(PM, PS, MM, IS);
  k_zhat<<<512,256,0,stream>>>(S, wmem, MM, IS, Gz);
  // ---- decoder ----
  k_convt<64,32,16,32><<<512,256,0,stream>>>(Gz, w_d1, b_d1, Cc);
  k_stats<32><<<512,256,0,stream>>>(Cc, 2097152, PT);
  k_finalize<32><<<1,256,0,stream>>>(PT, 512, 1.0/65536.0, gt1, bet1, SS);
  k_bnrelu<32><<<2048,256,0,stream>>>(Cc, SS, D, 524288);
  k_convt<32,16,16,64><<<1024,256,0,stream>>>(D, w_d2, b_d2, A);
  k_stats<16><<<512,256,0,stream>>>(A, 4194304, PT);
  k_finalize<16><<<1,256,0,stream>>>(PT, 512, 1.0/262144.0, gt2, bet2, SS);
  k_bnrelu<16><<<4096,256,0,stream>>>(A, SS, Bh, 1048576);
  k_convt_final<<<4096,256,0,stream>>>(Bh, w_d3, b_d3, out);
}

// Round 2
// 686.165 us; speedup vs baseline: 1.5031x; 1.5031x over previous
//
#include <hip/hip_runtime.h>
#include <math.h>

typedef __bf16 bf16x8 __attribute__((ext_vector_type(8)));
typedef __bf16 bf16x4 __attribute__((ext_vector_type(4)));
typedef float  f32x16 __attribute__((ext_vector_type(16)));

static __device__ __forceinline__ f32x16 zero16() {
  f32x16 v;
  #pragma unroll
  for (int i = 0; i < 16; ++i) v[i] = 0.f;
  return v;
}
static __device__ __forceinline__ unsigned short bfbits(__bf16 b) {
  return __builtin_bit_cast(unsigned short, b);
}

// ---------------- conv1: 1x1 stride2, 3->16 ----------------
__global__ __launch_bounds__(256) void k_conv1(const float* __restrict__ x,
    const float* __restrict__ w, const float* __restrict__ b, float* __restrict__ y) {
  int t = blockIdx.x*256 + threadIdx.x;        // 16*128*128 pixels
  int ox = t & 127, oy = (t >> 7) & 127, bb = t >> 14;
  const float* xp = x + ((size_t)((bb*256 + 2*oy)*256 + 2*ox))*3;
  float x0 = xp[0], x1 = xp[1], x2 = xp[2];
  float* yp = y + (size_t)t*16;
  #pragma unroll
  for (int c = 0; c < 16; ++c)
    yp[c] = b[c] + x0*w[c] + x1*w[16+c] + x2*w[32+c];
}

// ---------------- generic 3x3 stride-2 SAME conv (pad_beg=0) ----------------
template<int CIN,int COUT,int G,int HIN,int HOUT>
__global__ __launch_bounds__(256) void k_conv(const float* __restrict__ h,
    const float* __restrict__ w, const float* __restrict__ bias, float* __restrict__ y) {
  const int NGRP = COUT/G;
  int t = blockIdx.x*256 + threadIdx.x;
  int grp = t % NGRP;
  int px  = t / NGRP;
  int ox = px % HOUT, oy = (px/HOUT) % HOUT, bb = px/(HOUT*HOUT);
  float acc[G];
  #pragma unroll
  for (int j=0;j<G;++j) acc[j] = bias[grp*G+j];
  #pragma unroll
  for (int dy=0; dy<3; ++dy) {
    int iy = 2*oy + dy;
    if (iy >= HIN) continue;
    #pragma unroll
    for (int dx=0; dx<3; ++dx) {
      int ix = 2*ox + dx;
      if (ix >= HIN) continue;
      const float* hp = h + ((size_t)(bb*HIN + iy)*HIN + ix)*CIN;
      const float* wp = w + ((size_t)(dy*3+dx)*CIN)*COUT + grp*G;
      #pragma unroll
      for (int ci=0; ci<CIN; ++ci) {
        float v = hp[ci];
        #pragma unroll
        for (int j=0;j<G;++j) acc[j] = fmaf(v, wp[ci*COUT + j], acc[j]);
      }
    }
  }
  float* yp = y + (size_t)px*COUT + grp*G;
  #pragma unroll
  for (int j=0;j<G;++j) yp[j] = acc[j];
}

// ---------------- BN batch-stats partials ----------------
template<int C>
__global__ __launch_bounds__(256) void k_stats(const float* __restrict__ y, int nelem,
                                               float* __restrict__ partials) {
  int tid = threadIdx.x;
  int T = gridDim.x*256;
  float s = 0.f, q = 0.f;
  for (int e = blockIdx.x*256 + tid; e < nelem; e += T) {
    float v = y[e];
    s += v; q = fmaf(v, v, q);
  }
  #pragma unroll
  for (int off = C; off < 64; off <<= 1) {
    s += __shfl_xor(s, off);
    q += __shfl_xor(q, off);
  }
  __shared__ float lw[4][2*C];
  int wv = tid >> 6, lane = tid & 63;
  if (lane < C) { lw[wv][lane] = s; lw[wv][C+lane] = q; }
  __syncthreads();
  if (tid < 2*C)
    partials[(size_t)blockIdx.x*2*C + tid] = lw[0][tid]+lw[1][tid]+lw[2][tid]+lw[3][tid];
}

// ---------------- finalize: mean/var -> scale/shift ----------------
template<int C>
__global__ __launch_bounds__(256) void k_finalize(const float* __restrict__ partials, int nblk,
    double inv_n, const float* __restrict__ g, const float* __restrict__ be, float* __restrict__ ss) {
  const int NSTAT = 2*C;
  const int PER = 256/NSTAT;
  __shared__ double red[256];
  int tid = threadIdx.x;
  int stat = tid % NSTAT, sub = tid / NSTAT;
  double acc = 0.0;
  for (int i = sub; i < nblk; i += PER) acc += (double)partials[(size_t)i*NSTAT + stat];
  red[tid] = acc;
  __syncthreads();
  for (int off = PER>>1; off > 0; off >>= 1) {
    if (sub < off) red[tid] += red[tid + off*NSTAT];
    __syncthreads();
  }
  if (tid < C) {
    double mean = red[tid]*inv_n;
    double var  = red[C+tid]*inv_n - mean*mean;
    float scale = g[tid] * rsqrtf((float)var + 1e-3f);
    float shift = be[tid] - (float)mean*scale;
    ss[tid] = scale; ss[C+tid] = shift;
  }
}

// ---------------- BN apply + ReLU ----------------
template<int C>
__global__ __launch_bounds__(256) void k_bnrelu(const float* __restrict__ y,
    const float* __restrict__ ss, float* __restrict__ h, int n4) {
  int t = blockIdx.x*256 + threadIdx.x;
  if (t >= n4) return;
  float4 v = ((const float4*)y)[t];
  int c = (t*4) % C;
  float4 r;
  r.x = fmaxf(0.f, fmaf(v.x, ss[c+0], ss[C+c+0]));
  r.y = fmaxf(0.f, fmaf(v.y, ss[c+1], ss[C+c+1]));
  r.z = fmaxf(0.f, fmaf(v.z, ss[c+2], ss[C+c+2]));
  r.w = fmaxf(0.f, fmaf(v.w, ss[c+3], ss[C+c+3]));
  ((float4*)h)[t] = r;
}

// ================= memory module (MFMA, flash-style two-pass) =================

// prep z: split z and z^2 into bf16 hi/lo, [16384][64]
__global__ __launch_bounds__(256) void k_prep_z(const float* __restrict__ z,
    __bf16* __restrict__ ZH, __bf16* __restrict__ ZL,
    __bf16* __restrict__ Z2H, __bf16* __restrict__ Z2L) {
  int t = blockIdx.x*256 + threadIdx.x;   // handles 4 elems
  float4 v = ((const float4*)z)[t];
  float vv[4] = {v.x, v.y, v.z, v.w};
  bf16x4 h, l, h2, l2;
  #pragma unroll
  for (int i=0;i<4;++i) {
    float f = vv[i];
    __bf16 hb = (__bf16)f;
    h[i] = hb; l[i] = (__bf16)(f - (float)hb);
    float q = f*f;
    __bf16 qb = (__bf16)q;
    h2[i] = qb; l2[i] = (__bf16)(q - (float)qb);
  }
  ((bf16x4*)ZH)[t] = h;  ((bf16x4*)ZL)[t] = l;
  ((bf16x4*)Z2H)[t] = h2; ((bf16x4*)Z2L)[t] = l2;
}

// prep mem: [2000][64] -> padded [2048][64] bf16 splits (+squares) + transposed [64][2048]
__global__ __launch_bounds__(256) void k_prep_m(const float* __restrict__ mem,
    __bf16* __restrict__ MH, __bf16* __restrict__ ML,
    __bf16* __restrict__ M2H, __bf16* __restrict__ M2L,
    __bf16* __restrict__ MHT, __bf16* __restrict__ MLT) {
  int t = blockIdx.x*256 + threadIdx.x;   // 2048*16
  int n = t >> 4, c0 = (t & 15)*4;
  float4 v = make_float4(0.f,0.f,0.f,0.f);
  if (n < 2000) v = *(const float4*)(mem + (size_t)n*64 + c0);
  float vv[4] = {v.x, v.y, v.z, v.w};
  bf16x4 h, l, h2, l2;
  #pragma unroll
  for (int i=0;i<4;++i) {
    float f = vv[i];
    __bf16 hb = (__bf16)f;
    h[i] = hb; l[i] = (__bf16)(f - (float)hb);
    float q = f*f;
    __bf16 qb = (__bf16)q;
    h2[i] = qb; l2[i] = (__bf16)(q - (float)qb);
  }
  *(bf16x4*)(MH  + (size_t)n*64 + c0) = h;
  *(bf16x4*)(ML  + (size_t)n*64 + c0) = l;
  *(bf16x4*)(M2H + (size_t)n*64 + c0) = h2;
  *(bf16x4*)(M2L + (size_t)n*64 + c0) = l2;
  #pragma unroll
  for (int i=0;i<4;++i) {
    MHT[(size_t)(c0+i)*2048 + n] = h[i];
    MLT[(size_t)(c0+i)*2048 + n] = l[i];
  }
}

// pass1: scores via MFMA (C rows=n, cols=p) + online softmax partials per n-chunk
__global__ __launch_bounds__(512) void k_pass1(
    const __bf16* __restrict__ ZH, const __bf16* __restrict__ ZL,
    const __bf16* __restrict__ Z2H, const __bf16* __restrict__ Z2L,
    const __bf16* __restrict__ MH, const __bf16* __restrict__ ML,
    const __bf16* __restrict__ M2H, const __bf16* __restrict__ M2L,
    float* __restrict__ partM, float* __restrict__ partS) {
  int pb = blockIdx.x & 63, chunk = blockIdx.x >> 6;
  int wave = threadIdx.x >> 6, lane = threadIdx.x & 63;
  int p0 = pb*256 + wave*32;
  int col = lane & 31, hi = lane >> 5;
  // B-frags: z rows (col picks p, hi*8 picks k-half)
  bf16x8 bzh[4], bzl[4], b2h[4], b2l[4];
  size_t zoff = (size_t)(p0 + col)*64 + hi*8;
  #pragma unroll
  for (int ks=0;ks<4;++ks) {
    bzh[ks] = *(const bf16x8*)(ZH  + zoff + ks*16);
    bzl[ks] = *(const bf16x8*)(ZL  + zoff + ks*16);
    b2h[ks] = *(const bf16x8*)(Z2H + zoff + ks*16);
    b2l[ks] = *(const bf16x8*)(Z2L + zoff + ks*16);
  }
  float m = -3.4e38f, S = 0.f;
  int nbase = chunk*512;
  for (int t=0; t<16; ++t) {
    int n0 = nbase + t*32;
    if (n0 >= 2000) break;
    size_t arow = (size_t)(n0 + col)*64 + hi*8;
    f32x16 num = zero16(), den = zero16();
    #pragma unroll
    for (int ks=0;ks<4;++ks) {
      bf16x8 amh = *(const bf16x8*)(MH + arow + ks*16);
      bf16x8 aml = *(const bf16x8*)(ML + arow + ks*16);
      num = __builtin_amdgcn_mfma_f32_32x32x16_bf16(amh, bzh[ks], num, 0,0,0);
      num = __builtin_amdgcn_mfma_f32_32x32x16_bf16(amh, bzl[ks], num, 0,0,0);
      num = __builtin_amdgcn_mfma_f32_32x32x16_bf16(aml, bzh[ks], num, 0,0,0);
      bf16x8 a2h = *(const bf16x8*)(M2H + arow + ks*16);
      bf16x8 a2l = *(const bf16x8*)(M2L + arow + ks*16);
      den = __builtin_amdgcn_mfma_f32_32x32x16_bf16(a2h, b2h[ks], den, 0,0,0);
      den = __builtin_amdgcn_mfma_f32_32x32x16_bf16(a2h, b2l[ks], den, 0,0,0);
      den = __builtin_amdgcn_mfma_f32_32x32x16_bf16(a2l, b2h[ks], den, 0,0,0);
    }
    bool maskt = (n0 + 32 > 2000);
    float sv[16];
    float tmax = -3.4e38f;
    #pragma unroll
    for (int r=0;r<16;++r) {
      float s = (num[r] + 1e-12f) * __builtin_amdgcn_rcpf(den[r] + 1e-12f);
      if (maskt) {
        int nn = n0 + (r&3) + 8*(r>>2) + 4*hi;
        if (nn >= 2000) s = -3.4e38f;
      }
      sv[r] = s;
      tmax = fmaxf(tmax, s);
    }
    float mn = fmaxf(m, tmax);
    float ssum = 0.f;
    #pragma unroll
    for (int r=0;r<16;++r) ssum += __expf(sv[r] - mn);
    S = S*__expf(m - mn) + ssum;
    m = mn;
  }
  // combine lane-halves (same p lives in lane and lane+32)
  float mo = __shfl_xor(m, 32);
  float So = __shfl_xor(S, 32);
  float mf = fmaxf(m, mo);
  float Sf = S*__expf(m - mf) + So*__expf(mo - mf);
  if (lane < 32) {
    int p = p0 + col;
    partM[chunk*16384 + p] = mf;
    partS[chunk*16384 + p] = Sf;
  }
}

__global__ __launch_bounds__(256) void k_comb(const float* __restrict__ partM,
    const float* __restrict__ partS, float* __restrict__ M, float* __restrict__ IS) {
  int p = blockIdx.x*256 + threadIdx.x;
  float m = -3.4e38f;
  #pragma unroll
  for (int c=0;c<4;++c) m = fmaxf(m, partM[c*16384 + p]);
  float S = 0.f;
  #pragma unroll
  for (int c=0;c<4;++c) S += partS[c*16384 + p]*__expf(partM[c*16384 + p] - m);
  M[p] = m;
  IS[p] = __builtin_amdgcn_rcpf(S);
}

// pass2: recompute scores, shrinkage weights r, z_hat partial via MFMA
__global__ __launch_bounds__(512) void k_pass2(
    const __bf16* __restrict__ ZH, const __bf16* __restrict__ ZL,
    const __bf16* __restrict__ Z2H, const __bf16* __restrict__ Z2L,
    const __bf16* __restrict__ MH, const __bf16* __restrict__ ML,
    const __bf16* __restrict__ M2H, const __bf16* __restrict__ M2L,
    const __bf16* __restrict__ MHT, const __bf16* __restrict__ MLT,
    const float* __restrict__ Mv, const float* __restrict__ ISv,
    float* __restrict__ ZP) {
  __shared__ __bf16 lds[8*2560];      // per-wave rhT[32][40] + rlT[32][40]
  int pb = blockIdx.x & 63, chunk = blockIdx.x >> 6;
  int wave = threadIdx.x >> 6, lane = threadIdx.x & 63;
  int p0 = pb*256 + wave*32;
  int col = lane & 31, hi = lane >> 5;
  __bf16* rhT = lds + wave*2560;
  __bf16* rlT = rhT + 1280;
  bf16x8 bzh[4], bzl[4], b2h[4], b2l[4];
  size_t zoff = (size_t)(p0 + col)*64 + hi*8;
  #pragma unroll
  for (int ks=0;ks<4;++ks) {
    bzh[ks] = *(const bf16x8*)(ZH  + zoff + ks*16);
    bzl[ks] = *(const bf16x8*)(ZL  + zoff + ks*16);
    b2h[ks] = *(const bf16x8*)(Z2H + zoff + ks*16);
    b2l[ks] = *(const bf16x8*)(Z2L + zoff + ks*16);
  }
  float Mp = Mv[p0 + col], Ip = ISv[p0 + col];
  f32x16 za0 = zero16(), za1 = zero16();
  int nbase = chunk*512;
  for (int t=0; t<16; ++t) {
    int n0 = nbase + t*32;
    if (n0 >= 2000) break;
    size_t arow = (size_t)(n0 + col)*64 + hi*8;
    f32x16 num = zero16(), den = zero16();
    #pragma unroll
    for (int ks=0;ks<4;++ks) {
      bf16x8 amh = *(const bf16x8*)(MH + arow + ks*16);
      bf16x8 aml = *(const bf16x8*)(ML + arow + ks*16);
      num = __builtin_amdgcn_mfma_f32_32x32x16_bf16(amh, bzh[ks], num, 0,0,0);
      num = __builtin_amdgcn_mfma_f32_32x32x16_bf16(amh, bzl[ks], num, 0,0,0);
      num = __builtin_amdgcn_mfma_f32_32x32x16_bf16(aml, bzh[ks], num, 0,0,0);
      bf16x8 a2h = *(const bf16x8*)(M2H + arow + ks*16);
      bf16x8 a2l = *(const bf16x8*)(M2L + arow + ks*16);
      den = __builtin_amdgcn_mfma_f32_32x32x16_bf16(a2h, b2h[ks], den, 0,0,0);
      den = __builtin_amdgcn_mfma_f32_32x32x16_bf16(a2h, b2l[ks], den, 0,0,0);
      den = __builtin_amdgcn_mfma_f32_32x32x16_bf16(a2l, b2h[ks], den, 0,0,0);
    }
    // r = clip(relu(d)*att/(|d|+eps), 1e-12, 1);  att = exp(s-M)*IS
    float rv[16];
    #pragma unroll
    for (int r=0;r<16;++r) {
      float s = (num[r] + 1e-12f) * __builtin_amdgcn_rcpf(den[r] + 1e-12f);
      float att = __expf(s - Mp) * Ip;
      float d = att - 0.0005f;
      float rel = fmaxf(d, 0.f) * att * __builtin_amdgcn_rcpf(fabsf(d) + 1e-12f);
      rv[r] = fminf(fmaxf(rel, 1e-12f), 1.0f);
    }
    // transpose r to LDS as bf16 hi/lo:  rT[p=col][n-local]
    #pragma unroll
    for (int i=0;i<8;++i) {
      int row0 = ((2*i)&3) + 8*(i>>1) + 4*hi;
      float r0 = rv[2*i], r1 = rv[2*i+1];
      __bf16 h0 = (__bf16)r0, h1 = (__bf16)r1;
      __bf16 l0 = (__bf16)(r0 - (float)h0), l1 = (__bf16)(r1 - (float)h1);
      unsigned int uh = (unsigned int)bfbits(h0) | ((unsigned int)bfbits(h1) << 16);
      unsigned int ul = (unsigned int)bfbits(l0) | ((unsigned int)bfbits(l1) << 16);
      *(unsigned int*)(rhT + col*40 + row0) = uh;
      *(unsigned int*)(rlT + col*40 + row0) = ul;
    }
    // z_hat accumulate: C[row=p][col=c], A=r (LDS), B=mem^T
    #pragma unroll
    for (int ks=0;ks<2;++ks) {
      bf16x8 arh = *(const bf16x8*)(rhT + col*40 + ks*16 + hi*8);
      bf16x8 arl = *(const bf16x8*)(rlT + col*40 + ks*16 + hi*8);
      size_t bofs = (size_t)col*2048 + n0 + ks*16 + hi*8;
      bf16x8 bmh0 = *(const bf16x8*)(MHT + bofs);
      bf16x8 bml0 = *(const bf16x8*)(MLT + bofs);
      bf16x8 bmh1 = *(const bf16x8*)(MHT + bofs + (size_t)32*2048);
      bf16x8 bml1 = *(const bf16x8*)(MLT + bofs + (size_t)32*2048);
      za0 = __builtin_amdgcn_mfma_f32_32x32x16_bf16(arh, bmh0, za0, 0,0,0);
      za0 = __builtin_amdgcn_mfma_f32_32x32x16_bf16(arh, bml0, za0, 0,0,0);
      za0 = __builtin_amdgcn_mfma_f32_32x32x16_bf16(arl, bmh0, za0, 0,0,0);
      za1 = __builtin_amdgcn_mfma_f32_32x32x16_bf16(arh, bmh1, za1, 0,0,0);
      za1 = __builtin_amdgcn_mfma_f32_32x32x16_bf16(arh, bml1, za1, 0,0,0);
      za1 = __builtin_amdgcn_mfma_f32_32x32x16_bf16(arl, bmh1, za1, 0,0,0);
    }
  }
  size_t base = (size_t)chunk << 20;    // chunk*1048576
  #pragma unroll
  for (int r=0;r<16;++r) {
    int prow = (r&3) + 8*(r>>2) + 4*hi;
    size_t o = base + (size_t)(p0 + prow)*64 + col;
    ZP[o]      = za0[r];
    ZP[o + 32] = za1[r];
  }
}

__global__ __launch_bounds__(256) void k_zcomb(const float* __restrict__ ZP,
                                               float* __restrict__ Gz) {
  int t = blockIdx.x*256 + threadIdx.x;   // 1048576
  Gz[t] = ZP[t] + ZP[1048576+t] + ZP[2*1048576+t] + ZP[3*1048576+t];
}

// ---------------- conv_transpose 3x3 stride2 SAME ----------------
template<int CIN,int COUT,int G,int HIN>
__global__ __launch_bounds__(256) void k_convt(const float* __restrict__ zin,
    const float* __restrict__ w, const float* __restrict__ bias, float* __restrict__ y) {
  const int NGRP = COUT/G;
  const int HOUT = HIN*2;
  int t = blockIdx.x*256 + threadIdx.x;
  int grp = t % NGRP;
  int px  = t / NGRP;
  int n = px % HOUT, m = (px/HOUT) % HOUT, bb = px/(HOUT*HOUT);
  float acc[G];
  #pragma unroll
  for (int j=0;j<G;++j) acc[j] = bias[grp*G+j];
  for (int ki=0; ki<3; ++ki) {
    int mi = m - ki;
    if (mi & 1) continue;
    int i = mi >> 1;
    if (i < 0 || i >= HIN) continue;
    for (int kj=0; kj<3; ++kj) {
      int nj = n - kj;
      if (nj & 1) continue;
      int j2 = nj >> 1;
      if (j2 < 0 || j2 >= HIN) continue;
      const float* zp = zin + ((size_t)(bb*HIN + i)*HIN + j2)*CIN;
      float v[CIN];
      #pragma unroll
      for (int ci=0;ci<CIN;++ci) v[ci] = zp[ci];
      const float* wp = w + ((size_t)(ki*3+kj)*COUT + grp*G)*CIN;
      #pragma unroll
      for (int j=0;j<G;++j) {
        #pragma unroll
        for (int ci=0;ci<CIN;++ci)
          acc[j] = fmaf(v[ci], wp[j*CIN + ci], acc[j]);
      }
    }
  }
  float* yp = y + (size_t)px*COUT + grp*G;
  #pragma unroll
  for (int j=0;j<G;++j) yp[j] = acc[j];
}

// ---------------- final conv_transpose 16->3 + clip ----------------
__global__ __launch_bounds__(256) void k_convt_final(const float* __restrict__ zin,
    const float* __restrict__ w, const float* __restrict__ bias, float* __restrict__ out) {
  const int CIN=16, HIN=128, HOUT=256;
  int px = blockIdx.x*256 + threadIdx.x;   // 16*256*256
  int n = px % HOUT, m = (px/HOUT) % HOUT, bb = px/(HOUT*HOUT);
  float a0 = bias[0], a1 = bias[1], a2 = bias[2];
  for (int ki=0; ki<3; ++ki) {
    int mi = m - ki; if (mi & 1) continue; int i = mi >> 1; if (i < 0 || i >= HIN) continue;
    for (int kj=0; kj<3; ++kj) {
      int nj = n - kj; if (nj & 1) continue; int j2 = nj >> 1; if (j2 < 0 || j2 >= HIN) continue;
      const float* zp = zin + ((size_t)(bb*HIN + i)*HIN + j2)*CIN;
      const float* wp = w + (size_t)(ki*3+kj)*3*CIN;
      #pragma unroll
      for (int ci=0;ci<CIN;++ci) {
        float v = zp[ci];
        a0 = fmaf(v, wp[ci],       a0);
        a1 = fmaf(v, wp[CIN+ci],   a1);
        a2 = fmaf(v, wp[2*CIN+ci], a2);
      }
    }
  }
  float* op = out + (size_t)px*3;
  op[0] = fminf(fmaxf(a0, 1e-12f), 1.0f);
  op[1] = fminf(fmaxf(a1, 1e-12f), 1.0f);
  op[2] = fminf(fmaxf(a2, 1e-12f), 1.0f);
}

extern "C" void kernel_launch(void* const* d_in, const int* in_sizes, int n_in,
                              void* d_out, int out_size, void* d_ws, size_t ws_size,
                              hipStream_t stream) {
  const float* x    = (const float*)d_in[0];
  const float* w_e1 = (const float*)d_in[1];
  const float* b_e1 = (const float*)d_in[2];
  const float* g1   = (const float*)d_in[3];
  const float* be1  = (const float*)d_in[4];
  const float* w_e2 = (const float*)d_in[5];
  const float* b_e2 = (const float*)d_in[6];
  const float* g2   = (const float*)d_in[7];
  const float* be2  = (const float*)d_in[8];
  const float* w_e3 = (const float*)d_in[9];
  const float* b_e3 = (const float*)d_in[10];
  const float* g3   = (const float*)d_in[11];
  const float* be3  = (const float*)d_in[12];
  const float* wmem = (const float*)d_in[13];
  const float* w_d1 = (const float*)d_in[14];
  const float* b_d1 = (const float*)d_in[15];
  const float* gt1  = (const float*)d_in[16];
  const float* bet1 = (const float*)d_in[17];
  const float* w_d2 = (const float*)d_in[18];
  const float* b_d2 = (const float*)d_in[19];
  const float* gt2  = (const float*)d_in[20];
  const float* bet2 = (const float*)d_in[21];
  const float* w_d3 = (const float*)d_in[22];
  const float* b_d3 = (const float*)d_in[23];
  float* out = (float*)d_out;

  float* ws = (float*)d_ws;
  float* A  = ws;                    // 4194304
  float* Bh = A  + 4194304;          // 4194304
  float* Cc = Bh + 4194304;          // 2097152
  float* D  = Cc + 2097152;          // 2097152
  float* E  = D  + 2097152;          // 1048576
  float* F  = E  + 1048576;          // 1048576  z
  float* Gz = F  + 1048576;          // 1048576  zhat
  float* ZP = Gz + 1048576;          // 4194304  zhat partials [4][16384][64]
  float* bfbase = ZP + 4194304;
  __bf16* ZH  = (__bf16*)bfbase;                 // 16384*64 each
  __bf16* ZL  = ZH  + 16384*64;
  __bf16* Z2H = ZL  + 16384*64;
  __bf16* Z2L = Z2H + 16384*64;
  __bf16* MH  = Z2L + 16384*64;                  // 2048*64 each
  __bf16* ML  = MH  + 2048*64;
  __bf16* M2H = ML  + 2048*64;
  __bf16* M2L = M2H + 2048*64;
  __bf16* MHT = M2L + 2048*64;                   // 64*2048 each
  __bf16* MLT = MHT + 64*2048;
  float* PT   = (float*)(MLT + 64*2048);         // 131072 BN partials
  float* SS   = PT + 131072;                     // 256
  float* PM   = SS + 256;                        // 65536 partM
  float* PS   = PM + 65536;                      // 65536 partS
  float* MM   = PS + 65536;                      // 16384
  float* IS   = MM + 16384;                      // 16384
  (void)ws_size; (void)in_sizes; (void)n_in; (void)out_size;

  // ---- encoder ----
  k_conv1<<<1024,256,0,stream>>>(x, w_e1, b_e1, A);
  k_stats<16><<<512,256,0,stream>>>(A, 4194304, PT);
  k_finalize<16><<<1,256,0,stream>>>(PT, 512, 1.0/262144.0, g1, be1, SS);
  k_bnrelu<16><<<4096,256,0,stream>>>(A, SS, Bh, 1048576);
  k_conv<16,32,16,128,64><<<512,256,0,stream>>>(Bh, w_e2, b_e2, Cc);
  k_stats<32><<<512,256,0,stream>>>(Cc, 2097152, PT);
  k_finalize<32><<<1,256,0,stream>>>(PT, 512, 1.0/65536.0, g2, be2, SS);
  k_bnrelu<32><<<2048,256,0,stream>>>(Cc, SS, D, 524288);
  k_conv<32,64,8,64,32><<<512,256,0,stream>>>(D, w_e3, b_e3, E);
  k_stats<64><<<512,256,0,stream>>>(E, 1048576, PT);
  k_finalize<64><<<1,256,0,stream>>>(PT, 512, 1.0/16384.0, g3, be3, SS);
  k_bnrelu<64><<<1024,256,0,stream>>>(E, SS, F, 262144);
  // ---- memory addressing (MFMA two-pass) ----
  k_prep_m<<<128,256,0,stream>>>(wmem, MH, ML, M2H, M2L, MHT, MLT);
  k_prep_z<<<1024,256,0,stream>>>(F, ZH, ZL, Z2H, Z2L);
  k_pass1<<<256,512,0,stream>>>(ZH, ZL, Z2H, Z2L, MH, ML, M2H, M2L, PM, PS);
  k_comb<<<64,256,0,stream>>>(PM, PS, MM, IS);
  k_pass2<<<256,512,0,stream>>>(ZH, ZL, Z2H, Z2L, MH, ML, M2H, M2L, MHT, MLT, MM, IS, ZP);
  k_zcomb<<<4096,256,0,stream>>>(ZP, Gz);
  // ---- decoder ----
  k_convt<64,32,16,32><<<512,256,0,stream>>>(Gz, w_d1, b_d1, Cc);
  k_stats<32><<<512,256,0,stream>>>(Cc, 2097152, PT);
  k_finalize<32><<<1,256,0,stream>>>(PT, 512, 1.0/65536.0, gt1, bet1, SS);
  k_bnrelu<32><<<2048,256,0,stream>>>(Cc, SS, D, 524288);
  k_convt<32,16,16,64><<<1024,256,0,stream>>>(D, w_d2, b_d2, A);
  k_stats<16><<<512,256,0,stream>>>(A, 4194304, PT);
  k_finalize<16><<<1,256,0,stream>>>(PT, 512, 1.0/262144.0, gt2, bet2, SS);
  k_bnrelu<16><<<4096,256,0,stream>>>(A, SS, Bh, 1048576);
  k_convt_final<<<4096,256,0,stream>>>(Bh, w_d3, b_d3, out);
}

// Round 3
// 561.053 us; speedup vs baseline: 1.8383x; 1.2230x over previous
//
#include <hip/hip_runtime.h>
#include <math.h>

typedef __bf16 bf16x8 __attribute__((ext_vector_type(8)));
typedef __bf16 bf16x4 __attribute__((ext_vector_type(4)));
typedef float  f32x16 __attribute__((ext_vector_type(16)));

static __device__ __forceinline__ f32x16 zero16() {
  f32x16 v;
  #pragma unroll
  for (int i = 0; i < 16; ++i) v[i] = 0.f;
  return v;
}
static __device__ __forceinline__ unsigned short bfbits(__bf16 b) {
  return __builtin_bit_cast(unsigned short, b);
}

// ---------------- conv1: 1x1 stride2, 3->16 ----------------
__global__ __launch_bounds__(256) void k_conv1(const float* __restrict__ x,
    const float* __restrict__ w, const float* __restrict__ b, float* __restrict__ y) {
  int t = blockIdx.x*256 + threadIdx.x;        // 16*128*128 pixels
  int ox = t & 127, oy = (t >> 7) & 127, bb = t >> 14;
  const float* xp = x + ((size_t)((bb*256 + 2*oy)*256 + 2*ox))*3;
  float x0 = xp[0], x1 = xp[1], x2 = xp[2];
  float4* yp = (float4*)(y + (size_t)t*16);
  #pragma unroll
  for (int g = 0; g < 4; ++g) {
    float4 r;
    r.x = b[g*4+0] + x0*w[g*4+0] + x1*w[16+g*4+0] + x2*w[32+g*4+0];
    r.y = b[g*4+1] + x0*w[g*4+1] + x1*w[16+g*4+1] + x2*w[32+g*4+1];
    r.z = b[g*4+2] + x0*w[g*4+2] + x1*w[16+g*4+2] + x2*w[32+g*4+2];
    r.w = b[g*4+3] + x0*w[g*4+3] + x1*w[16+g*4+3] + x2*w[32+g*4+3];
    yp[g] = r;
  }
}

// ---------------- forward 3x3 stride-2 SAME conv, optional fused input BN+ReLU ----------
// w layout HWIO [dy][dx][cin][cout]; grid = (PXTOT/(256*PX)) * CSPLIT blocks of 256
template<int CIN,int COUT,int CSPLIT,int PX,int HIN,int HOUT,bool BN>
__global__ __launch_bounds__(256) void k_conv_bn(const float* __restrict__ in,
    const float* __restrict__ w, const float* __restrict__ bias,
    const float* __restrict__ ss, float* __restrict__ y) {
  const int COUTT = COUT/CSPLIT;
  const int NW4 = COUTT/4;
  __shared__ float4 wlds[9*CIN*NW4];
  int bid = blockIdx.x;
  int cq  = bid % CSPLIT;
  int pxb = bid / CSPLIT;
  int c0  = cq*COUTT;
  for (int e = threadIdx.x; e < 9*CIN*NW4; e += 256) {
    int r = e / NW4, cg = e % NW4;
    wlds[e] = *(const float4*)(w + (size_t)r*COUT + c0 + cg*4);
  }
  __syncthreads();
  int t0 = pxb*(256*PX) + threadIdx.x;
  float4 acc[PX][NW4];
  #pragma unroll
  for (int g=0; g<NW4; ++g) {
    float4 bi = *(const float4*)(bias + c0 + g*4);
    #pragma unroll
    for (int p=0; p<PX; ++p) acc[p][g] = bi;
  }
  int oxv[PX], oyv[PX], bv[PX];
  #pragma unroll
  for (int p=0; p<PX; ++p) {
    int t = t0 + p*256;
    oxv[p] = t % HOUT; oyv[p] = (t/HOUT) % HOUT; bv[p] = t/(HOUT*HOUT);
  }
  #pragma unroll 1
  for (int dy=0; dy<3; ++dy) {
    #pragma unroll 1
    for (int dx=0; dx<3; ++dx) {
      int tap = dy*3+dx;
      #pragma unroll
      for (int p=0; p<PX; ++p) {
        int iy = 2*oyv[p] + dy, ix = 2*oxv[p] + dx;
        if (iy < HIN && ix < HIN) {
          const float* bp = in + ((size_t)(bv[p]*HIN + iy)*HIN + ix)*CIN;
          #pragma unroll
          for (int ci4=0; ci4<CIN/4; ++ci4) {
            float4 v = *(const float4*)(bp + ci4*4);
            if (BN) {
              float4 sc = *(const float4*)(ss + ci4*4);
              float4 sh = *(const float4*)(ss + CIN + ci4*4);
              v.x = fmaxf(0.f, fmaf(v.x, sc.x, sh.x));
              v.y = fmaxf(0.f, fmaf(v.y, sc.y, sh.y));
              v.z = fmaxf(0.f, fmaf(v.z, sc.z, sh.z));
              v.w = fmaxf(0.f, fmaf(v.w, sc.w, sh.w));
            }
            float va[4] = {v.x, v.y, v.z, v.w};
            #pragma unroll
            for (int k=0;k<4;++k) {
              float vk = va[k];
              #pragma unroll
              for (int g=0; g<NW4; ++g) {
                float4 w4 = wlds[(tap*CIN + ci4*4 + k)*NW4 + g];
                acc[p][g].x = fmaf(vk, w4.x, acc[p][g].x);
                acc[p][g].y = fmaf(vk, w4.y, acc[p][g].y);
                acc[p][g].z = fmaf(vk, w4.z, acc[p][g].z);
                acc[p][g].w = fmaf(vk, w4.w, acc[p][g].w);
              }
            }
          }
        }
      }
    }
  }
  #pragma unroll
  for (int p=0;p<PX;++p) {
    float4* yp = (float4*)(y + (size_t)(t0 + p*256)*COUT + c0);
    #pragma unroll
    for (int g=0;g<NW4;++g) yp[g] = acc[p][g];
  }
}

// ---------------- BN batch-stats partials ----------------
template<int C>
__global__ __launch_bounds__(256) void k_stats(const float* __restrict__ y, int nelem,
                                               float* __restrict__ partials) {
  int tid = threadIdx.x;
  int T = gridDim.x*256;
  float s = 0.f, q = 0.f;
  for (int e = blockIdx.x*256 + tid; e < nelem; e += T) {
    float v = y[e];
    s += v; q = fmaf(v, v, q);
  }
  #pragma unroll
  for (int off = C; off < 64; off <<= 1) {
    s += __shfl_xor(s, off);
    q += __shfl_xor(q, off);
  }
  __shared__ float lw[4][2*C];
  int wv = tid >> 6, lane = tid & 63;
  if (lane < C) { lw[wv][lane] = s; lw[wv][C+lane] = q; }
  __syncthreads();
  if (tid < 2*C)
    partials[(size_t)blockIdx.x*2*C + tid] = lw[0][tid]+lw[1][tid]+lw[2][tid]+lw[3][tid];
}

// ---------------- finalize: mean/var -> scale/shift ----------------
template<int C>
__global__ __launch_bounds__(256) void k_finalize(const float* __restrict__ partials, int nblk,
    double inv_n, const float* __restrict__ g, const float* __restrict__ be, float* __restrict__ ss) {
  const int NSTAT = 2*C;
  const int PER = 256/NSTAT;
  __shared__ double red[256];
  int tid = threadIdx.x;
  int stat = tid % NSTAT, sub = tid / NSTAT;
  double acc = 0.0;
  for (int i = sub; i < nblk; i += PER) acc += (double)partials[(size_t)i*NSTAT + stat];
  red[tid] = acc;
  __syncthreads();
  for (int off = PER>>1; off > 0; off >>= 1) {
    if (sub < off) red[tid] += red[tid + off*NSTAT];
    __syncthreads();
  }
  if (tid < C) {
    double mean = red[tid]*inv_n;
    double var  = red[C+tid]*inv_n - mean*mean;
    float scale = g[tid] * rsqrtf((float)var + 1e-3f);
    float shift = be[tid] - (float)mean*scale;
    ss[tid] = scale; ss[C+tid] = shift;
  }
}

// ================= memory module (MFMA, flash-style two-pass) =================

// prep z: fused BN3+ReLU, then split z and z^2 into bf16 hi/lo, [16384][64]
__global__ __launch_bounds__(256) void k_prep_z(const float* __restrict__ y3,
    const float* __restrict__ ss,
    __bf16* __restrict__ ZH, __bf16* __restrict__ ZL,
    __bf16* __restrict__ Z2H, __bf16* __restrict__ Z2L) {
  int t = blockIdx.x*256 + threadIdx.x;   // handles 4 elems
  float4 v = ((const float4*)y3)[t];
  int c0 = (t*4) & 63;
  float4 sc = *(const float4*)(ss + c0);
  float4 sh = *(const float4*)(ss + 64 + c0);
  float vv[4];
  vv[0] = fmaxf(0.f, fmaf(v.x, sc.x, sh.x));
  vv[1] = fmaxf(0.f, fmaf(v.y, sc.y, sh.y));
  vv[2] = fmaxf(0.f, fmaf(v.z, sc.z, sh.z));
  vv[3] = fmaxf(0.f, fmaf(v.w, sc.w, sh.w));
  bf16x4 h, l, h2, l2;
  #pragma unroll
  for (int i=0;i<4;++i) {
    float f = vv[i];
    __bf16 hb = (__bf16)f;
    h[i] = hb; l[i] = (__bf16)(f - (float)hb);
    float q = f*f;
    __bf16 qb = (__bf16)q;
    h2[i] = qb; l2[i] = (__bf16)(q - (float)qb);
  }
  ((bf16x4*)ZH)[t] = h;  ((bf16x4*)ZL)[t] = l;
  ((bf16x4*)Z2H)[t] = h2; ((bf16x4*)Z2L)[t] = l2;
}

// prep mem: [2000][64] -> padded [2048][64] bf16 splits (+squares) + transposed [64][2048]
__global__ __launch_bounds__(256) void k_prep_m(const float* __restrict__ mem,
    __bf16* __restrict__ MH, __bf16* __restrict__ ML,
    __bf16* __restrict__ M2H, __bf16* __restrict__ M2L,
    __bf16* __restrict__ MHT, __bf16* __restrict__ MLT) {
  int t = blockIdx.x*256 + threadIdx.x;   // 2048*16
  int n = t >> 4, c0 = (t & 15)*4;
  float4 v = make_float4(0.f,0.f,0.f,0.f);
  if (n < 2000) v = *(const float4*)(mem + (size_t)n*64 + c0);
  float vv[4] = {v.x, v.y, v.z, v.w};
  bf16x4 h, l, h2, l2;
  #pragma unroll
  for (int i=0;i<4;++i) {
    float f = vv[i];
    __bf16 hb = (__bf16)f;
    h[i] = hb; l[i] = (__bf16)(f - (float)hb);
    float q = f*f;
    __bf16 qb = (__bf16)q;
    h2[i] = qb; l2[i] = (__bf16)(q - (float)qb);
  }
  *(bf16x4*)(MH  + (size_t)n*64 + c0) = h;
  *(bf16x4*)(ML  + (size_t)n*64 + c0) = l;
  *(bf16x4*)(M2H + (size_t)n*64 + c0) = h2;
  *(bf16x4*)(M2L + (size_t)n*64 + c0) = l2;
  #pragma unroll
  for (int i=0;i<4;++i) {
    MHT[(size_t)(c0+i)*2048 + n] = h[i];
    MLT[(size_t)(c0+i)*2048 + n] = l[i];
  }
}

// pass1: scores via MFMA (C rows=n, cols=p) + online softmax partials per n-chunk
__global__ __launch_bounds__(512) void k_pass1(
    const __bf16* __restrict__ ZH, const __bf16* __restrict__ ZL,
    const __bf16* __restrict__ Z2H, const __bf16* __restrict__ Z2L,
    const __bf16* __restrict__ MH, const __bf16* __restrict__ ML,
    const __bf16* __restrict__ M2H, const __bf16* __restrict__ M2L,
    float* __restrict__ partM, float* __restrict__ partS) {
  int pb = blockIdx.x & 63, chunk = blockIdx.x >> 6;
  int wave = threadIdx.x >> 6, lane = threadIdx.x & 63;
  int p0 = pb*256 + wave*32;
  int col = lane & 31, hi = lane >> 5;
  bf16x8 bzh[4], bzl[4], b2h[4], b2l[4];
  size_t zoff = (size_t)(p0 + col)*64 + hi*8;
  #pragma unroll
  for (int ks=0;ks<4;++ks) {
    bzh[ks] = *(const bf16x8*)(ZH  + zoff + ks*16);
    bzl[ks] = *(const bf16x8*)(ZL  + zoff + ks*16);
    b2h[ks] = *(const bf16x8*)(Z2H + zoff + ks*16);
    b2l[ks] = *(const bf16x8*)(Z2L + zoff + ks*16);
  }
  float m = -3.4e38f, S = 0.f;
  int nbase = chunk*512;
  for (int t=0; t<16; ++t) {
    int n0 = nbase + t*32;
    if (n0 >= 2000) break;
    size_t arow = (size_t)(n0 + col)*64 + hi*8;
    f32x16 num = zero16(), den = zero16();
    #pragma unroll
    for (int ks=0;ks<4;++ks) {
      bf16x8 amh = *(const bf16x8*)(MH + arow + ks*16);
      bf16x8 aml = *(const bf16x8*)(ML + arow + ks*16);
      num = __builtin_amdgcn_mfma_f32_32x32x16_bf16(amh, bzh[ks], num, 0,0,0);
      num = __builtin_amdgcn_mfma_f32_32x32x16_bf16(amh, bzl[ks], num, 0,0,0);
      num = __builtin_amdgcn_mfma_f32_32x32x16_bf16(aml, bzh[ks], num, 0,0,0);
      bf16x8 a2h = *(const bf16x8*)(M2H + arow + ks*16);
      bf16x8 a2l = *(const bf16x8*)(M2L + arow + ks*16);
      den = __builtin_amdgcn_mfma_f32_32x32x16_bf16(a2h, b2h[ks], den, 0,0,0);
      den = __builtin_amdgcn_mfma_f32_32x32x16_bf16(a2h, b2l[ks], den, 0,0,0);
      den = __builtin_amdgcn_mfma_f32_32x32x16_bf16(a2l, b2h[ks], den, 0,0,0);
    }
    bool maskt = (n0 + 32 > 2000);
    float sv[16];
    float tmax = -3.4e38f;
    #pragma unroll
    for (int r=0;r<16;++r) {
      float s = (num[r] + 1e-12f) * __builtin_amdgcn_rcpf(den[r] + 1e-12f);
      if (maskt) {
        int nn = n0 + (r&3) + 8*(r>>2) + 4*hi;
        if (nn >= 2000) s = -3.4e38f;
      }
      sv[r] = s;
      tmax = fmaxf(tmax, s);
    }
    float mn = fmaxf(m, tmax);
    float ssum = 0.f;
    #pragma unroll
    for (int r=0;r<16;++r) ssum += __expf(sv[r] - mn);
    S = S*__expf(m - mn) + ssum;
    m = mn;
  }
  float mo = __shfl_xor(m, 32);
  float So = __shfl_xor(S, 32);
  float mf = fmaxf(m, mo);
  float Sf = S*__expf(m - mf) + So*__expf(mo - mf);
  if (lane < 32) {
    int p = p0 + col;
    partM[chunk*16384 + p] = mf;
    partS[chunk*16384 + p] = Sf;
  }
}

__global__ __launch_bounds__(256) void k_comb(const float* __restrict__ partM,
    const float* __restrict__ partS, float* __restrict__ M, float* __restrict__ IS) {
  int p = blockIdx.x*256 + threadIdx.x;
  float m = -3.4e38f;
  #pragma unroll
  for (int c=0;c<4;++c) m = fmaxf(m, partM[c*16384 + p]);
  float S = 0.f;
  #pragma unroll
  for (int c=0;c<4;++c) S += partS[c*16384 + p]*__expf(partM[c*16384 + p] - m);
  M[p] = m;
  IS[p] = __builtin_amdgcn_rcpf(S);
}

// pass2: recompute scores, shrinkage weights r, z_hat partial via MFMA
__global__ __launch_bounds__(512) void k_pass2(
    const __bf16* __restrict__ ZH, const __bf16* __restrict__ ZL,
    const __bf16* __restrict__ Z2H, const __bf16* __restrict__ Z2L,
    const __bf16* __restrict__ MH, const __bf16* __restrict__ ML,
    const __bf16* __restrict__ M2H, const __bf16* __restrict__ M2L,
    const __bf16* __restrict__ MHT, const __bf16* __restrict__ MLT,
    const float* __restrict__ Mv, const float* __restrict__ ISv,
    float* __restrict__ ZP) {
  __shared__ __bf16 lds[8*2560];      // per-wave rhT[32][40] + rlT[32][40]
  int pb = blockIdx.x & 63, chunk = blockIdx.x >> 6;
  int wave = threadIdx.x >> 6, lane = threadIdx.x & 63;
  int p0 = pb*256 + wave*32;
  int col = lane & 31, hi = lane >> 5;
  __bf16* rhT = lds + wave*2560;
  __bf16* rlT = rhT + 1280;
  bf16x8 bzh[4], bzl[4], b2h[4], b2l[4];
  size_t zoff = (size_t)(p0 + col)*64 + hi*8;
  #pragma unroll
  for (int ks=0;ks<4;++ks) {
    bzh[ks] = *(const bf16x8*)(ZH  + zoff + ks*16);
    bzl[ks] = *(const bf16x8*)(ZL  + zoff + ks*16);
    b2h[ks] = *(const bf16x8*)(Z2H + zoff + ks*16);
    b2l[ks] = *(const bf16x8*)(Z2L + zoff + ks*16);
  }
  float Mp = Mv[p0 + col], Ip = ISv[p0 + col];
  f32x16 za0 = zero16(), za1 = zero16();
  int nbase = chunk*512;
  for (int t=0; t<16; ++t) {
    int n0 = nbase + t*32;
    if (n0 >= 2000) break;
    size_t arow = (size_t)(n0 + col)*64 + hi*8;
    f32x16 num = zero16(), den = zero16();
    #pragma unroll
    for (int ks=0;ks<4;++ks) {
      bf16x8 amh = *(const bf16x8*)(MH + arow + ks*16);
      bf16x8 aml = *(const bf16x8*)(ML + arow + ks*16);
      num = __builtin_amdgcn_mfma_f32_32x32x16_bf16(amh, bzh[ks], num, 0,0,0);
      num = __builtin_amdgcn_mfma_f32_32x32x16_bf16(amh, bzl[ks], num, 0,0,0);
      num = __builtin_amdgcn_mfma_f32_32x32x16_bf16(aml, bzh[ks], num, 0,0,0);
      bf16x8 a2h = *(const bf16x8*)(M2H + arow + ks*16);
      bf16x8 a2l = *(const bf16x8*)(M2L + arow + ks*16);
      den = __builtin_amdgcn_mfma_f32_32x32x16_bf16(a2h, b2h[ks], den, 0,0,0);
      den = __builtin_amdgcn_mfma_f32_32x32x16_bf16(a2h, b2l[ks], den, 0,0,0);
      den = __builtin_amdgcn_mfma_f32_32x32x16_bf16(a2l, b2h[ks], den, 0,0,0);
    }
    float rv[16];
    #pragma unroll
    for (int r=0;r<16;++r) {
      float s = (num[r] + 1e-12f) * __builtin_amdgcn_rcpf(den[r] + 1e-12f);
      float att = __expf(s - Mp) * Ip;
      float d = att - 0.0005f;
      float rel = fmaxf(d, 0.f) * att * __builtin_amdgcn_rcpf(fabsf(d) + 1e-12f);
      rv[r] = fminf(fmaxf(rel, 1e-12f), 1.0f);
    }
    #pragma unroll
    for (int i=0;i<8;++i) {
      int row0 = ((2*i)&3) + 8*(i>>1) + 4*hi;
      float r0 = rv[2*i], r1 = rv[2*i+1];
      __bf16 h0 = (__bf16)r0, h1 = (__bf16)r1;
      __bf16 l0 = (__bf16)(r0 - (float)h0), l1 = (__bf16)(r1 - (float)h1);
      unsigned int uh = (unsigned int)bfbits(h0) | ((unsigned int)bfbits(h1) << 16);
      unsigned int ul = (unsigned int)bfbits(l0) | ((unsigned int)bfbits(l1) << 16);
      *(unsigned int*)(rhT + col*40 + row0) = uh;
      *(unsigned int*)(rlT + col*40 + row0) = ul;
    }
    #pragma unroll
    for (int ks=0;ks<2;++ks) {
      bf16x8 arh = *(const bf16x8*)(rhT + col*40 + ks*16 + hi*8);
      bf16x8 arl = *(const bf16x8*)(rlT + col*40 + ks*16 + hi*8);
      size_t bofs = (size_t)col*2048 + n0 + ks*16 + hi*8;
      bf16x8 bmh0 = *(const bf16x8*)(MHT + bofs);
      bf16x8 bml0 = *(const bf16x8*)(MLT + bofs);
      bf16x8 bmh1 = *(const bf16x8*)(MHT + bofs + (size_t)32*2048);
      bf16x8 bml1 = *(const bf16x8*)(MLT + bofs + (size_t)32*2048);
      za0 = __builtin_amdgcn_mfma_f32_32x32x16_bf16(arh, bmh0, za0, 0,0,0);
      za0 = __builtin_amdgcn_mfma_f32_32x32x16_bf16(arh, bml0, za0, 0,0,0);
      za0 = __builtin_amdgcn_mfma_f32_32x32x16_bf16(arl, bmh0, za0, 0,0,0);
      za1 = __builtin_amdgcn_mfma_f32_32x32x16_bf16(arh, bmh1, za1, 0,0,0);
      za1 = __builtin_amdgcn_mfma_f32_32x32x16_bf16(arh, bml1, za1, 0,0,0);
      za1 = __builtin_amdgcn_mfma_f32_32x32x16_bf16(arl, bmh1, za1, 0,0,0);
    }
  }
  size_t base = (size_t)chunk << 20;
  #pragma unroll
  for (int r=0;r<16;++r) {
    int prow = (r&3) + 8*(r>>2) + 4*hi;
    size_t o = base + (size_t)(p0 + prow)*64 + col;
    ZP[o]      = za0[r];
    ZP[o + 32] = za1[r];
  }
}

__global__ __launch_bounds__(256) void k_zcomb(const float* __restrict__ ZP,
                                               float* __restrict__ Gz) {
  int t = blockIdx.x*256 + threadIdx.x;   // 1048576
  Gz[t] = ZP[t] + ZP[1048576+t] + ZP[2*1048576+t] + ZP[3*1048576+t];
}

// ---------------- conv_transpose 3x3 stride2 SAME, parity-class blocks ----------------
// w layout [ki][kj][COUT][CIN]; class (pm,pn): m=2my+pm, taps ki=pm+2ti, i=my-ti
template<int CIN,int COUT,int CSPLIT,int PX,int HIN,bool BN>
__global__ __launch_bounds__(256) void k_convt_bn(const float* __restrict__ in,
    const float* __restrict__ w, const float* __restrict__ bias,
    const float* __restrict__ ss, float* __restrict__ y) {
  const int COUTT = COUT/CSPLIT;
  const int HOUT = 2*HIN;
  const int PXB = 16*HIN*HIN/(256*PX);
  __shared__ float4 wlds[4*COUTT*(CIN/4)];
  int bid = blockIdx.x;
  int cq = bid % CSPLIT; int rest = bid / CSPLIT;
  int cls = rest % 4;    int pxb = rest / 4;
  int pm = cls >> 1, pn = cls & 1;
  int c0 = cq*COUTT;
  int NTI = (pm == 0) ? 2 : 1;
  int NTJ = (pn == 0) ? 2 : 1;
  int NT = NTI*NTJ;
  for (int e = threadIdx.x; e < NT*COUTT*(CIN/4); e += 256) {
    int tl = e / (COUTT*(CIN/4));
    int rem = e % (COUTT*(CIN/4));
    int cc = rem / (CIN/4), ci4 = rem % (CIN/4);
    int ki = pm + 2*(tl / NTJ), kj = pn + 2*(tl % NTJ);
    wlds[e] = *(const float4*)(w + ((size_t)(ki*3+kj)*COUT + c0 + cc)*CIN + ci4*4);
  }
  __syncthreads();
  int t0 = pxb*(256*PX) + threadIdx.x;
  float acc[PX][COUTT];
  #pragma unroll
  for (int cc=0;cc<COUTT;++cc) {
    float bi = bias[c0+cc];
    #pragma unroll
    for (int p=0;p<PX;++p) acc[p][cc] = bi;
  }
  int nxv[PX], myv[PX], bv[PX];
  #pragma unroll
  for (int p=0;p<PX;++p) {
    int t = t0 + p*256;
    nxv[p] = t % HIN; myv[p] = (t/HIN) % HIN; bv[p] = t/(HIN*HIN);
  }
  #pragma unroll 1
  for (int ti=0; ti<NTI; ++ti) {
    #pragma unroll 1
    for (int tj=0; tj<NTJ; ++tj) {
      int tl = ti*NTJ + tj;
      #pragma unroll
      for (int p=0;p<PX;++p) {
        int i = myv[p] - ti, j = nxv[p] - tj;
        if (i >= 0 && j >= 0) {
          const float* bp = in + ((size_t)(bv[p]*HIN + i)*HIN + j)*CIN;
          #pragma unroll
          for (int ci4=0; ci4<CIN/4; ++ci4) {
            float4 v = *(const float4*)(bp + ci4*4);
            if (BN) {
              float4 sc = *(const float4*)(ss + ci4*4);
              float4 sh = *(const float4*)(ss + CIN + ci4*4);
              v.x = fmaxf(0.f, fmaf(v.x, sc.x, sh.x));
              v.y = fmaxf(0.f, fmaf(v.y, sc.y, sh.y));
              v.z = fmaxf(0.f, fmaf(v.z, sc.z, sh.z));
              v.w = fmaxf(0.f, fmaf(v.w, sc.w, sh.w));
            }
            #pragma unroll
            for (int cc=0;cc<COUTT;++cc) {
              float4 w4 = wlds[(tl*COUTT + cc)*(CIN/4) + ci4];
              float a = acc[p][cc];
              a = fmaf(v.x, w4.x, a);
              a = fmaf(v.y, w4.y, a);
              a = fmaf(v.z, w4.z, a);
              a = fmaf(v.w, w4.w, a);
              acc[p][cc] = a;
            }
          }
        }
      }
    }
  }
  #pragma unroll
  for (int p=0;p<PX;++p) {
    int m = 2*myv[p] + pm, n = 2*nxv[p] + pn;
    float* yp = y + ((size_t)(bv[p]*HOUT + m)*HOUT + n)*COUT + c0;
    #pragma unroll
    for (int g=0;g<COUTT/4;++g)
      ((float4*)yp)[g] = make_float4(acc[p][g*4], acc[p][g*4+1], acc[p][g*4+2], acc[p][g*4+3]);
  }
}

// ---------------- final conv_transpose 16->3 + input BN+ReLU + clip ----------------
__global__ __launch_bounds__(256) void k_convt_final(const float* __restrict__ in,
    const float* __restrict__ w, const float* __restrict__ bias,
    const float* __restrict__ ss, float* __restrict__ out) {
  const int CIN=16, HIN=128, HOUT=256;
  __shared__ float4 wlds[4*3*4];     // [tap][c][ci4]
  int cls = blockIdx.x & 3;
  int pxb = blockIdx.x >> 2;
  int pm = cls >> 1, pn = cls & 1;
  int NTI = (pm == 0) ? 2 : 1;
  int NTJ = (pn == 0) ? 2 : 1;
  int NT = NTI*NTJ;
  if (threadIdx.x < NT*3*4) {
    int e = threadIdx.x;
    int tl = e / 12, rem = e % 12;
    int c = rem / 4, ci4 = rem % 4;
    int ki = pm + 2*(tl / NTJ), kj = pn + 2*(tl % NTJ);
    wlds[e] = *(const float4*)(w + ((size_t)(ki*3+kj)*3 + c)*CIN + ci4*4);
  }
  __syncthreads();
  int t = pxb*256 + threadIdx.x;
  int nx = t % HIN, my = (t/HIN) % HIN, bb = t/(HIN*HIN);
  float a0 = bias[0], a1 = bias[1], a2 = bias[2];
  #pragma unroll 1
  for (int ti=0; ti<NTI; ++ti) {
    #pragma unroll 1
    for (int tj=0; tj<NTJ; ++tj) {
      int tl = ti*NTJ + tj;
      int i = my - ti, j = nx - tj;
      if (i >= 0 && j >= 0) {
        const float* bp = in + ((size_t)(bb*HIN + i)*HIN + j)*CIN;
        #pragma unroll
        for (int ci4=0; ci4<4; ++ci4) {
          float4 v = *(const float4*)(bp + ci4*4);
          float4 sc = *(const float4*)(ss + ci4*4);
          float4 sh = *(const float4*)(ss + CIN + ci4*4);
          v.x = fmaxf(0.f, fmaf(v.x, sc.x, sh.x));
          v.y = fmaxf(0.f, fmaf(v.y, sc.y, sh.y));
          v.z = fmaxf(0.f, fmaf(v.z, sc.z, sh.z));
          v.w = fmaxf(0.f, fmaf(v.w, sc.w, sh.w));
          float4 w0 = wlds[(tl*3 + 0)*4 + ci4];
          float4 w1 = wlds[(tl*3 + 1)*4 + ci4];
          float4 w2 = wlds[(tl*3 + 2)*4 + ci4];
          a0 = fmaf(v.x, w0.x, a0); a0 = fmaf(v.y, w0.y, a0);
          a0 = fmaf(v.z, w0.z, a0); a0 = fmaf(v.w, w0.w, a0);
          a1 = fmaf(v.x, w1.x, a1); a1 = fmaf(v.y, w1.y, a1);
          a1 = fmaf(v.z, w1.z, a1); a1 = fmaf(v.w, w1.w, a1);
          a2 = fmaf(v.x, w2.x, a2); a2 = fmaf(v.y, w2.y, a2);
          a2 = fmaf(v.z, w2.z, a2); a2 = fmaf(v.w, w2.w, a2);
        }
      }
    }
  }
  int m = 2*my + pm, n = 2*nx + pn;
  float* op = out + ((size_t)(bb*HOUT + m)*HOUT + n)*3;
  op[0] = fminf(fmaxf(a0, 1e-12f), 1.0f);
  op[1] = fminf(fmaxf(a1, 1e-12f), 1.0f);
  op[2] = fminf(fmaxf(a2, 1e-12f), 1.0f);
}

extern "C" void kernel_launch(void* const* d_in, const int* in_sizes, int n_in,
                              void* d_out, int out_size, void* d_ws, size_t ws_size,
                              hipStream_t stream) {
  const float* x    = (const float*)d_in[0];
  const float* w_e1 = (const float*)d_in[1];
  const float* b_e1 = (const float*)d_in[2];
  const float* g1   = (const float*)d_in[3];
  const float* be1  = (const float*)d_in[4];
  const float* w_e2 = (const float*)d_in[5];
  const float* b_e2 = (const float*)d_in[6];
  const float* g2   = (const float*)d_in[7];
  const float* be2  = (const float*)d_in[8];
  const float* w_e3 = (const float*)d_in[9];
  const float* b_e3 = (const float*)d_in[10];
  const float* g3   = (const float*)d_in[11];
  const float* be3  = (const float*)d_in[12];
  const float* wmem = (const float*)d_in[13];
  const float* w_d1 = (const float*)d_in[14];
  const float* b_d1 = (const float*)d_in[15];
  const float* gt1  = (const float*)d_in[16];
  const float* bet1 = (const float*)d_in[17];
  const float* w_d2 = (const float*)d_in[18];
  const float* b_d2 = (const float*)d_in[19];
  const float* gt2  = (const float*)d_in[20];
  const float* bet2 = (const float*)d_in[21];
  const float* w_d3 = (const float*)d_in[22];
  const float* b_d3 = (const float*)d_in[23];
  float* out = (float*)d_out;

  float* ws = (float*)d_ws;
  float* A  = ws;                    // 4194304  y1 / t2 raw
  float* Bh = A  + 4194304;          // 4194304  (unused)
  float* Cc = Bh + 4194304;          // 2097152  y2 / t1 raw
  float* D  = Cc + 2097152;          // 2097152  (unused)
  float* E  = D  + 2097152;          // 1048576  y3 raw
  float* F  = E  + 1048576;          // 1048576  (unused)
  float* Gz = F  + 1048576;          // 1048576  zhat
  float* ZP = Gz + 1048576;          // 4194304  zhat partials [4][16384][64]
  float* bfbase = ZP + 4194304;
  __bf16* ZH  = (__bf16*)bfbase;                 // 16384*64 each
  __bf16* ZL  = ZH  + 16384*64;
  __bf16* Z2H = ZL  + 16384*64;
  __bf16* Z2L = Z2H + 16384*64;
  __bf16* MH  = Z2L + 16384*64;                  // 2048*64 each
  __bf16* ML  = MH  + 2048*64;
  __bf16* M2H = ML  + 2048*64;
  __bf16* M2L = M2H + 2048*64;
  __bf16* MHT = M2L + 2048*64;                   // 64*2048 each
  __bf16* MLT = MHT + 64*2048;
  float* PT   = (float*)(MLT + 64*2048);         // 131072 BN partials
  float* SS   = PT + 131072;                     // 256
  float* PM   = SS + 256;                        // 65536 partM
  float* PS   = PM + 65536;                      // 65536 partS
  float* MM   = PS + 65536;                      // 16384
  float* IS   = MM + 16384;                      // 16384
  (void)ws_size; (void)in_sizes; (void)n_in; (void)out_size;

  // ---- encoder ----
  k_conv1<<<1024,256,0,stream>>>(x, w_e1, b_e1, A);
  k_stats<16><<<512,256,0,stream>>>(A, 4194304, PT);
  k_finalize<16><<<1,256,0,stream>>>(PT, 512, 1.0/262144.0, g1, be1, SS);
  k_conv_bn<16,32,2,2,128,64,true><<<256,256,0,stream>>>(A, w_e2, b_e2, SS, Cc);
  k_stats<32><<<512,256,0,stream>>>(Cc, 2097152, PT);
  k_finalize<32><<<1,256,0,stream>>>(PT, 512, 1.0/65536.0, g2, be2, SS);
  k_conv_bn<32,64,8,2,64,32,true><<<256,256,0,stream>>>(Cc, w_e3, b_e3, SS, E);
  k_stats<64><<<512,256,0,stream>>>(E, 1048576, PT);
  k_finalize<64><<<1,256,0,stream>>>(PT, 512, 1.0/16384.0, g3, be3, SS);
  // ---- memory addressing (MFMA two-pass; BN3+ReLU fused into prep_z) ----
  k_prep_m<<<128,256,0,stream>>>(wmem, MH, ML, M2H, M2L, MHT, MLT);
  k_prep_z<<<1024,256,0,stream>>>(E, SS, ZH, ZL, Z2H, Z2L);
  k_pass1<<<256,512,0,stream>>>(ZH, ZL, Z2H, Z2L, MH, ML, M2H, M2L, PM, PS);
  k_comb<<<64,256,0,stream>>>(PM, PS, MM, IS);
  k_pass2<<<256,512,0,stream>>>(ZH, ZL, Z2H, Z2L, MH, ML, M2H, M2L, MHT, MLT, MM, IS, ZP);
  k_zcomb<<<4096,256,0,stream>>>(ZP, Gz);
  // ---- decoder ----
  k_convt_bn<64,32,2,2,32,false><<<256,256,0,stream>>>(Gz, w_d1, b_d1, nullptr, Cc);
  k_stats<32><<<512,256,0,stream>>>(Cc, 2097152, PT);
  k_finalize<32><<<1,256,0,stream>>>(PT, 512, 1.0/65536.0, gt1, bet1, SS);
  k_convt_bn<32,16,1,2,64,true><<<512,256,0,stream>>>(Cc, w_d2, b_d2, SS, A);
  k_stats<16><<<512,256,0,stream>>>(A, 4194304, PT);
  k_finalize<16><<<1,256,0,stream>>>(PT, 512, 1.0/262144.0, gt2, bet2, SS);
  k_convt_final<<<4096,256,0,stream>>>(A, w_d3, b_d3, SS, out);
}

// Round 4
// 459.072 us; speedup vs baseline: 2.2467x; 1.2221x over previous
//
#include <hip/hip_runtime.h>
#include <math.h>

typedef __bf16 bf16x8 __attribute__((ext_vector_type(8)));
typedef __bf16 bf16x4 __attribute__((ext_vector_type(4)));
typedef float  f32x16 __attribute__((ext_vector_type(16)));

static __device__ __forceinline__ f32x16 zero16() {
  f32x16 v;
  #pragma unroll
  for (int i = 0; i < 16; ++i) v[i] = 0.f;
  return v;
}
static __device__ __forceinline__ unsigned int bfbits(__bf16 b) {
  return (unsigned int)__builtin_bit_cast(unsigned short, b);
}
static __device__ __forceinline__ bf16x8 mk8(unsigned int a, unsigned int b,
                                             unsigned int c, unsigned int d) {
  uint4 t; t.x = a; t.y = b; t.z = c; t.w = d;
  return __builtin_bit_cast(bf16x8, t);
}

// ---------------- conv1: 1x1 stride2, 3->16 ----------------
__global__ __launch_bounds__(256) void k_conv1(const float* __restrict__ x,
    const float* __restrict__ w, const float* __restrict__ b, float* __restrict__ y) {
  int t = blockIdx.x*256 + threadIdx.x;        // 16*128*128 pixels
  int ox = t & 127, oy = (t >> 7) & 127, bb = t >> 14;
  const float* xp = x + ((size_t)((bb*256 + 2*oy)*256 + 2*ox))*3;
  float x0 = xp[0], x1 = xp[1], x2 = xp[2];
  float4* yp = (float4*)(y + (size_t)t*16);
  #pragma unroll
  for (int g = 0; g < 4; ++g) {
    float4 r;
    r.x = b[g*4+0] + x0*w[g*4+0] + x1*w[16+g*4+0] + x2*w[32+g*4+0];
    r.y = b[g*4+1] + x0*w[g*4+1] + x1*w[16+g*4+1] + x2*w[32+g*4+1];
    r.z = b[g*4+2] + x0*w[g*4+2] + x1*w[16+g*4+2] + x2*w[32+g*4+2];
    r.w = b[g*4+3] + x0*w[g*4+3] + x1*w[16+g*4+3] + x2*w[32+g*4+3];
    yp[g] = r;
  }
}

// ---------------- BN batch-stats partials (for conv1 output only) ----------------
template<int C>
__global__ __launch_bounds__(256) void k_stats(const float* __restrict__ y, int nelem,
                                               float* __restrict__ partials) {
  int tid = threadIdx.x;
  int T = gridDim.x*256;
  float s = 0.f, q = 0.f;
  for (int e = blockIdx.x*256 + tid; e < nelem; e += T) {
    float v = y[e];
    s += v; q = fmaf(v, v, q);
  }
  #pragma unroll
  for (int off = C; off < 64; off <<= 1) {
    s += __shfl_xor(s, off);
    q += __shfl_xor(q, off);
  }
  __shared__ float lw[4][2*C];
  int wv = tid >> 6, lane = tid & 63;
  if (lane < C) { lw[wv][lane] = s; lw[wv][C+lane] = q; }
  __syncthreads();
  if (tid < 2*C)
    partials[(size_t)blockIdx.x*2*C + tid] = lw[0][tid]+lw[1][tid]+lw[2][tid]+lw[3][tid];
}

// ---------------- finalize: partials([blk][2*COUTT], blk%CSPLIT=chgroup) -> scale/shift ---
template<int C,int CSPLIT>
__global__ __launch_bounds__(256) void k_finalize2(const float* __restrict__ partials, int nblk,
    double inv_n, const float* __restrict__ g, const float* __restrict__ be, float* __restrict__ ss) {
  const int COUTT = C/CSPLIT;
  const int NSTAT = 2*C;
  const int PER = 256/NSTAT;
  __shared__ double red[256];
  int tid = threadIdx.x;
  int st = tid % NSTAT, sub = tid / NSTAT;
  int c = st % C, kind = st / C;
  int cq = c / COUTT, j = c % COUTT;
  int nb = nblk / CSPLIT;
  double acc = 0.0;
  for (int i = sub; i < nb; i += PER) {
    int b = cq + i*CSPLIT;
    acc += (double)partials[(size_t)b*2*COUTT + kind*COUTT + j];
  }
  red[tid] = acc;
  __syncthreads();
  for (int off = PER>>1; off > 0; off >>= 1) {
    if (sub < off) red[tid] += red[tid + off*NSTAT];
    __syncthreads();
  }
  if (tid < C) {
    double mean = red[tid]*inv_n;
    double var  = red[C+tid]*inv_n - mean*mean;
    float scale = g[tid] * rsqrtf((float)var + 1e-3f);
    float shift = be[tid] - (float)mean*scale;
    ss[tid] = scale; ss[C+tid] = shift;
  }
}

// ---------------- forward 3x3 stride-2 SAME conv, fused input BN+ReLU + fused stats -----
template<int CIN,int COUT,int CSPLIT,int HIN,int HOUT,bool BN>
__global__ __launch_bounds__(256) void k_conv_bn(const float* __restrict__ in,
    const float* __restrict__ w, const float* __restrict__ bias,
    const float* __restrict__ ss, float* __restrict__ y, float* __restrict__ partials) {
  const int COUTT = COUT/CSPLIT;
  const int NW4 = COUTT/4;
  __shared__ float4 wlds[9*CIN*NW4];
  int bid = blockIdx.x;
  int cq  = bid % CSPLIT;
  int pxb = bid / CSPLIT;
  int c0  = cq*COUTT;
  for (int e = threadIdx.x; e < 9*CIN*NW4; e += 256) {
    int r = e / NW4, cg = e % NW4;
    wlds[e] = *(const float4*)(w + (size_t)r*COUT + c0 + cg*4);
  }
  __syncthreads();
  int t0 = pxb*256 + threadIdx.x;
  float4 acc[NW4];
  #pragma unroll
  for (int g=0; g<NW4; ++g) acc[g] = *(const float4*)(bias + c0 + g*4);
  int ox = t0 % HOUT, oy = (t0/HOUT) % HOUT, bb = t0/(HOUT*HOUT);
  #pragma unroll 1
  for (int dy=0; dy<3; ++dy) {
    #pragma unroll 1
    for (int dx=0; dx<3; ++dx) {
      int tap = dy*3+dx;
      int iy = 2*oy + dy, ix = 2*ox + dx;
      if (iy < HIN && ix < HIN) {
        const float* bp = in + ((size_t)(bb*HIN + iy)*HIN + ix)*CIN;
        #pragma unroll
        for (int ci4=0; ci4<CIN/4; ++ci4) {
          float4 v = *(const float4*)(bp + ci4*4);
          if (BN) {
            float4 sc = *(const float4*)(ss + ci4*4);
            float4 sh = *(const float4*)(ss + CIN + ci4*4);
            v.x = fmaxf(0.f, fmaf(v.x, sc.x, sh.x));
            v.y = fmaxf(0.f, fmaf(v.y, sc.y, sh.y));
            v.z = fmaxf(0.f, fmaf(v.z, sc.z, sh.z));
            v.w = fmaxf(0.f, fmaf(v.w, sc.w, sh.w));
          }
          float va[4] = {v.x, v.y, v.z, v.w};
          #pragma unroll
          for (int k=0;k<4;++k) {
            float vk = va[k];
            #pragma unroll
            for (int g=0; g<NW4; ++g) {
              float4 w4 = wlds[(tap*CIN + ci4*4 + k)*NW4 + g];
              acc[g].x = fmaf(vk, w4.x, acc[g].x);
              acc[g].y = fmaf(vk, w4.y, acc[g].y);
              acc[g].z = fmaf(vk, w4.z, acc[g].z);
              acc[g].w = fmaf(vk, w4.w, acc[g].w);
            }
          }
        }
      }
    }
  }
  float4* yp = (float4*)(y + (size_t)t0*COUT + c0);
  #pragma unroll
  for (int g=0;g<NW4;++g) yp[g] = acc[g];
  // fused BN batch-stats partial (sum, sumsq over this block's outputs)
  float4 s4[NW4], q4[NW4];
  #pragma unroll
  for (int g=0; g<NW4; ++g) {
    s4[g] = acc[g];
    q4[g] = make_float4(acc[g].x*acc[g].x, acc[g].y*acc[g].y,
                        acc[g].z*acc[g].z, acc[g].w*acc[g].w);
  }
  #pragma unroll
  for (int off=1; off<64; off<<=1) {
    #pragma unroll
    for (int g=0; g<NW4; ++g) {
      s4[g].x += __shfl_xor(s4[g].x, off); s4[g].y += __shfl_xor(s4[g].y, off);
      s4[g].z += __shfl_xor(s4[g].z, off); s4[g].w += __shfl_xor(s4[g].w, off);
      q4[g].x += __shfl_xor(q4[g].x, off); q4[g].y += __shfl_xor(q4[g].y, off);
      q4[g].z += __shfl_xor(q4[g].z, off); q4[g].w += __shfl_xor(q4[g].w, off);
    }
  }
  __shared__ float red[4][2*COUTT];
  int wv = threadIdx.x >> 6, lane = threadIdx.x & 63;
  if (lane == 0) {
    #pragma unroll
    for (int g=0; g<NW4; ++g) {
      *(float4*)&red[wv][g*4]         = s4[g];
      *(float4*)&red[wv][COUTT + g*4] = q4[g];
    }
  }
  __syncthreads();
  if (threadIdx.x < 2*COUTT)
    partials[(size_t)bid*2*COUTT + threadIdx.x] =
      red[0][threadIdx.x]+red[1][threadIdx.x]+red[2][threadIdx.x]+red[3][threadIdx.x];
}

// ================= memory module (MFMA, flash-style two-pass) =================

// prep z: fused BN3+ReLU, then split z and z^2 into bf16 hi/lo, [16384][64]
__global__ __launch_bounds__(256) void k_prep_z(const float* __restrict__ y3,
    const float* __restrict__ ss,
    __bf16* __restrict__ ZH, __bf16* __restrict__ ZL,
    __bf16* __restrict__ Z2H, __bf16* __restrict__ Z2L) {
  int t = blockIdx.x*256 + threadIdx.x;   // handles 4 elems
  float4 v = ((const float4*)y3)[t];
  int c0 = (t*4) & 63;
  float4 sc = *(const float4*)(ss + c0);
  float4 sh = *(const float4*)(ss + 64 + c0);
  float vv[4];
  vv[0] = fmaxf(0.f, fmaf(v.x, sc.x, sh.x));
  vv[1] = fmaxf(0.f, fmaf(v.y, sc.y, sh.y));
  vv[2] = fmaxf(0.f, fmaf(v.z, sc.z, sh.z));
  vv[3] = fmaxf(0.f, fmaf(v.w, sc.w, sh.w));
  bf16x4 h, l, h2, l2;
  #pragma unroll
  for (int i=0;i<4;++i) {
    float f = vv[i];
    __bf16 hb = (__bf16)f;
    h[i] = hb; l[i] = (__bf16)(f - (float)hb);
    float q = f*f;
    __bf16 qb = (__bf16)q;
    h2[i] = qb; l2[i] = (__bf16)(q - (float)qb);
  }
  ((bf16x4*)ZH)[t] = h;  ((bf16x4*)ZL)[t] = l;
  ((bf16x4*)Z2H)[t] = h2; ((bf16x4*)Z2L)[t] = l2;
}

// prep mem: [2000][64] -> padded [2048][64] bf16 splits (+squares) + transposed [64][2048]
__global__ __launch_bounds__(256) void k_prep_m(const float* __restrict__ mem,
    __bf16* __restrict__ MH, __bf16* __restrict__ ML,
    __bf16* __restrict__ M2H, __bf16* __restrict__ M2L,
    __bf16* __restrict__ MHT, __bf16* __restrict__ MLT) {
  int t = blockIdx.x*256 + threadIdx.x;   // 2048*16
  int n = t >> 4, c0 = (t & 15)*4;
  float4 v = make_float4(0.f,0.f,0.f,0.f);
  if (n < 2000) v = *(const float4*)(mem + (size_t)n*64 + c0);
  float vv[4] = {v.x, v.y, v.z, v.w};
  bf16x4 h, l, h2, l2;
  #pragma unroll
  for (int i=0;i<4;++i) {
    float f = vv[i];
    __bf16 hb = (__bf16)f;
    h[i] = hb; l[i] = (__bf16)(f - (float)hb);
    float q = f*f;
    __bf16 qb = (__bf16)q;
    h2[i] = qb; l2[i] = (__bf16)(q - (float)qb);
  }
  *(bf16x4*)(MH  + (size_t)n*64 + c0) = h;
  *(bf16x4*)(ML  + (size_t)n*64 + c0) = l;
  *(bf16x4*)(M2H + (size_t)n*64 + c0) = h2;
  *(bf16x4*)(M2L + (size_t)n*64 + c0) = l2;
  #pragma unroll
  for (int i=0;i<4;++i) {
    MHT[(size_t)(c0+i)*2048 + n] = h[i];
    MLT[(size_t)(c0+i)*2048 + n] = l[i];
  }
}

// pass1: scores via MFMA (C rows=n, cols=p) + online softmax partials per 256-n chunk
__global__ __launch_bounds__(512) void k_pass1(
    const __bf16* __restrict__ ZH, const __bf16* __restrict__ ZL,
    const __bf16* __restrict__ Z2H, const __bf16* __restrict__ Z2L,
    const __bf16* __restrict__ MH, const __bf16* __restrict__ ML,
    const __bf16* __restrict__ M2H, const __bf16* __restrict__ M2L,
    float* __restrict__ partM, float* __restrict__ partS) {
  int pb = blockIdx.x & 63, chunk = blockIdx.x >> 6;   // 64 pb x 8 chunks
  int wave = threadIdx.x >> 6, lane = threadIdx.x & 63;
  int p0 = pb*256 + wave*32;
  int col = lane & 31, hi = lane >> 5;
  bf16x8 bzh[4], bzl[4], b2h[4], b2l[4];
  size_t zoff = (size_t)(p0 + col)*64 + hi*8;
  #pragma unroll
  for (int ks=0;ks<4;++ks) {
    bzh[ks] = *(const bf16x8*)(ZH  + zoff + ks*16);
    bzl[ks] = *(const bf16x8*)(ZL  + zoff + ks*16);
    b2h[ks] = *(const bf16x8*)(Z2H + zoff + ks*16);
    b2l[ks] = *(const bf16x8*)(Z2L + zoff + ks*16);
  }
  float m = -3.4e38f, S = 0.f;
  int nbase = chunk*256;
  #pragma unroll 2
  for (int t=0; t<8; ++t) {
    int n0 = nbase + t*32;
    size_t arow = (size_t)(n0 + col)*64 + hi*8;
    f32x16 num = zero16(), den = zero16();
    #pragma unroll
    for (int ks=0;ks<4;++ks) {
      bf16x8 amh = *(const bf16x8*)(MH + arow + ks*16);
      bf16x8 aml = *(const bf16x8*)(ML + arow + ks*16);
      num = __builtin_amdgcn_mfma_f32_32x32x16_bf16(amh, bzh[ks], num, 0,0,0);
      num = __builtin_amdgcn_mfma_f32_32x32x16_bf16(amh, bzl[ks], num, 0,0,0);
      num = __builtin_amdgcn_mfma_f32_32x32x16_bf16(aml, bzh[ks], num, 0,0,0);
      bf16x8 a2h = *(const bf16x8*)(M2H + arow + ks*16);
      bf16x8 a2l = *(const bf16x8*)(M2L + arow + ks*16);
      den = __builtin_amdgcn_mfma_f32_32x32x16_bf16(a2h, b2h[ks], den, 0,0,0);
      den = __builtin_amdgcn_mfma_f32_32x32x16_bf16(a2h, b2l[ks], den, 0,0,0);
      den = __builtin_amdgcn_mfma_f32_32x32x16_bf16(a2l, b2h[ks], den, 0,0,0);
    }
    bool maskt = (n0 + 32 > 2000);
    float sv[16];
    float tmax = -3.4e38f;
    #pragma unroll
    for (int r=0;r<16;++r) {
      float s = (num[r] + 1e-12f) * __builtin_amdgcn_rcpf(den[r] + 1e-12f);
      if (maskt) {
        int nn = n0 + (r&3) + 8*(r>>2) + 4*hi;
        if (nn >= 2000) s = -3.4e38f;
      }
      sv[r] = s;
      tmax = fmaxf(tmax, s);
    }
    float mn = fmaxf(m, tmax);
    float ssum = 0.f;
    #pragma unroll
    for (int r=0;r<16;++r) ssum += __expf(sv[r] - mn);
    S = S*__expf(m - mn) + ssum;
    m = mn;
  }
  float mo = __shfl_xor(m, 32);
  float So = __shfl_xor(S, 32);
  float mf = fmaxf(m, mo);
  float Sf = S*__expf(m - mf) + So*__expf(mo - mf);
  if (lane < 32) {
    int p = p0 + col;
    partM[chunk*16384 + p] = mf;
    partS[chunk*16384 + p] = Sf;
  }
}

// pass2: recompute scores, shrinkage weights r, z_hat partial via MFMA.
// r-transpose done fully in-register via quad packing + lane-half shuffles.
__global__ __launch_bounds__(512) void k_pass2(
    const __bf16* __restrict__ ZH, const __bf16* __restrict__ ZL,
    const __bf16* __restrict__ Z2H, const __bf16* __restrict__ Z2L,
    const __bf16* __restrict__ MH, const __bf16* __restrict__ ML,
    const __bf16* __restrict__ M2H, const __bf16* __restrict__ M2L,
    const __bf16* __restrict__ MHT, const __bf16* __restrict__ MLT,
    const float* __restrict__ partM, const float* __restrict__ partS,
    float* __restrict__ ZP) {
  int pb = blockIdx.x & 63, chunk = blockIdx.x >> 6;
  int wave = threadIdx.x >> 6, lane = threadIdx.x & 63;
  int p0 = pb*256 + wave*32;
  int col = lane & 31, hi = lane >> 5;
  bf16x8 bzh[4], bzl[4], b2h[4], b2l[4];
  size_t zoff = (size_t)(p0 + col)*64 + hi*8;
  #pragma unroll
  for (int ks=0;ks<4;++ks) {
    bzh[ks] = *(const bf16x8*)(ZH  + zoff + ks*16);
    bzl[ks] = *(const bf16x8*)(ZL  + zoff + ks*16);
    b2h[ks] = *(const bf16x8*)(Z2H + zoff + ks*16);
    b2l[ks] = *(const bf16x8*)(Z2L + zoff + ks*16);
  }
  // inline softmax-normalizer combine (replaces k_comb)
  int p = p0 + col;
  float pmv[8];
  float Mp = -3.4e38f;
  #pragma unroll
  for (int c=0;c<8;++c) { pmv[c] = partM[c*16384 + p]; Mp = fmaxf(Mp, pmv[c]); }
  float Ssum = 0.f;
  #pragma unroll
  for (int c=0;c<8;++c) Ssum += partS[c*16384 + p] * __expf(pmv[c] - Mp);
  float Ip = __builtin_amdgcn_rcpf(Ssum);
  f32x16 za0 = zero16(), za1 = zero16();
  int nbase = chunk*256;
  #pragma unroll 2
  for (int t=0; t<8; ++t) {
    int n0 = nbase + t*32;
    size_t arow = (size_t)(n0 + col)*64 + hi*8;
    f32x16 num = zero16(), den = zero16();
    #pragma unroll
    for (int ks=0;ks<4;++ks) {
      bf16x8 amh = *(const bf16x8*)(MH + arow + ks*16);
      bf16x8 aml = *(const bf16x8*)(ML + arow + ks*16);
      num = __builtin_amdgcn_mfma_f32_32x32x16_bf16(amh, bzh[ks], num, 0,0,0);
      num = __builtin_amdgcn_mfma_f32_32x32x16_bf16(amh, bzl[ks], num, 0,0,0);
      num = __builtin_amdgcn_mfma_f32_32x32x16_bf16(aml, bzh[ks], num, 0,0,0);
      bf16x8 a2h = *(const bf16x8*)(M2H + arow + ks*16);
      bf16x8 a2l = *(const bf16x8*)(M2L + arow + ks*16);
      den = __builtin_amdgcn_mfma_f32_32x32x16_bf16(a2h, b2h[ks], den, 0,0,0);
      den = __builtin_amdgcn_mfma_f32_32x32x16_bf16(a2h, b2l[ks], den, 0,0,0);
      den = __builtin_amdgcn_mfma_f32_32x32x16_bf16(a2l, b2h[ks], den, 0,0,0);
    }
    bool maskt = (n0 + 32 > 2000);
    float rv[16];
    #pragma unroll
    for (int r=0;r<16;++r) {
      float s = (num[r] + 1e-12f) * __builtin_amdgcn_rcpf(den[r] + 1e-12f);
      float att = __expf(s - Mp) * Ip;
      float d = att - 0.0005f;
      float rel = fmaxf(d, 0.f) * att * __builtin_amdgcn_rcpf(fabsf(d) + 1e-12f);
      float rr = fminf(fmaxf(rel, 1e-12f), 1.0f);
      if (maskt) {
        int nn = n0 + (r&3) + 8*(r>>2) + 4*hi;
        if (nn >= 2000) rr = 0.f;
      }
      rv[r] = rr;
    }
    // pack quads to bf16 hi/lo: quad qd covers rows {0..3}+8*qd (+4*hi)
    unsigned int qh[8], ql[8];
    #pragma unroll
    for (int qd=0; qd<4; ++qd) {
      #pragma unroll
      for (int pr=0; pr<2; ++pr) {
        float r0 = rv[qd*4 + pr*2], r1 = rv[qd*4 + pr*2 + 1];
        __bf16 h0 = (__bf16)r0, h1 = (__bf16)r1;
        __bf16 l0 = (__bf16)(r0 - (float)h0), l1 = (__bf16)(r1 - (float)h1);
        qh[qd*2+pr] = bfbits(h0) | (bfbits(h1) << 16);
        ql[qd*2+pr] = bfbits(l0) | (bfbits(l1) << 16);
      }
    }
    unsigned int qhp[8], qlp[8];
    #pragma unroll
    for (int i=0;i<8;++i) {
      qhp[i] = (unsigned int)__shfl_xor((int)qh[i], 32);
      qlp[i] = (unsigned int)__shfl_xor((int)ql[i], 32);
    }
    // A-frags: frag1 = k(n-local) 0..15, frag2 = 16..31
    bf16x8 f1h = hi ? mk8(qhp[2],qhp[3],qh[2],qh[3]) : mk8(qh[0],qh[1],qhp[0],qhp[1]);
    bf16x8 f1l = hi ? mk8(qlp[2],qlp[3],ql[2],ql[3]) : mk8(ql[0],ql[1],qlp[0],qlp[1]);
    bf16x8 f2h = hi ? mk8(qhp[6],qhp[7],qh[6],qh[7]) : mk8(qh[4],qh[5],qhp[4],qhp[5]);
    bf16x8 f2l = hi ? mk8(qlp[6],qlp[7],ql[6],ql[7]) : mk8(ql[4],ql[5],qlp[4],qlp[5]);
    #pragma unroll
    for (int kh=0; kh<2; ++kh) {
      bf16x8 fh = kh ? f2h : f1h;
      bf16x8 fl = kh ? f2l : f1l;
      size_t bofs = (size_t)col*2048 + n0 + kh*16 + hi*8;
      bf16x8 bmh0 = *(const bf16x8*)(MHT + bofs);
      bf16x8 bml0 = *(const bf16x8*)(MLT + bofs);
      bf16x8 bmh1 = *(const bf16x8*)(MHT + bofs + (size_t)32*2048);
      bf16x8 bml1 = *(const bf16x8*)(MLT + bofs + (size_t)32*2048);
      za0 = __builtin_amdgcn_mfma_f32_32x32x16_bf16(fh, bmh0, za0, 0,0,0);
      za0 = __builtin_amdgcn_mfma_f32_32x32x16_bf16(fh, bml0, za0, 0,0,0);
      za0 = __builtin_amdgcn_mfma_f32_32x32x16_bf16(fl, bmh0, za0, 0,0,0);
      za1 = __builtin_amdgcn_mfma_f32_32x32x16_bf16(fh, bmh1, za1, 0,0,0);
      za1 = __builtin_amdgcn_mfma_f32_32x32x16_bf16(fh, bml1, za1, 0,0,0);
      za1 = __builtin_amdgcn_mfma_f32_32x32x16_bf16(fl, bmh1, za1, 0,0,0);
    }
  }
  size_t base = (size_t)chunk << 20;
  #pragma unroll
  for (int r=0;r<16;++r) {
    int prow = (r&3) + 8*(r>>2) + 4*hi;
    size_t o = base + (size_t)(p0 + prow)*64 + col;
    ZP[o]      = za0[r];
    ZP[o + 32] = za1[r];
  }
}

__global__ __launch_bounds__(256) void k_zcomb(const float* __restrict__ ZP,
                                               float* __restrict__ Gz) {
  int t = blockIdx.x*256 + threadIdx.x;   // 1048576
  float a = 0.f;
  #pragma unroll
  for (int c=0;c<8;++c) a += ZP[(size_t)c*1048576 + t];
  Gz[t] = a;
}

// ---------------- conv_transpose 3x3 stride2 SAME, parity-class blocks + fused stats ----
template<int CIN,int COUT,int CSPLIT,int HIN,bool BN>
__global__ __launch_bounds__(256) void k_convt_bn(const float* __restrict__ in,
    const float* __restrict__ w, const float* __restrict__ bias,
    const float* __restrict__ ss, float* __restrict__ y, float* __restrict__ partials) {
  const int COUTT = COUT/CSPLIT;
  const int HOUT = 2*HIN;
  __shared__ float4 wlds[4*COUTT*(CIN/4)];
  int bid = blockIdx.x;
  int cq = bid % CSPLIT; int rest = bid / CSPLIT;
  int cls = rest % 4;    int pxb = rest / 4;
  int pm = cls >> 1, pn = cls & 1;
  int c0 = cq*COUTT;
  int NTI = (pm == 0) ? 2 : 1;
  int NTJ = (pn == 0) ? 2 : 1;
  int NT = NTI*NTJ;
  for (int e = threadIdx.x; e < NT*COUTT*(CIN/4); e += 256) {
    int tl = e / (COUTT*(CIN/4));
    int rem = e % (COUTT*(CIN/4));
    int cc = rem / (CIN/4), ci4 = rem % (CIN/4);
    int ki = pm + 2*(tl / NTJ), kj = pn + 2*(tl % NTJ);
    wlds[e] = *(const float4*)(w + ((size_t)(ki*3+kj)*COUT + c0 + cc)*CIN + ci4*4);
  }
  __syncthreads();
  int t0 = pxb*256 + threadIdx.x;
  float acc[COUTT];
  #pragma unroll
  for (int cc=0;cc<COUTT;++cc) acc[cc] = bias[c0+cc];
  int nx = t0 % HIN, my = (t0/HIN) % HIN, bb = t0/(HIN*HIN);
  #pragma unroll 1
  for (int ti=0; ti<NTI; ++ti) {
    #pragma unroll 1
    for (int tj=0; tj<NTJ; ++tj) {
      int tl = ti*NTJ + tj;
      int i = my - ti, j = nx - tj;
      if (i >= 0 && j >= 0) {
        const float* bp = in + ((size_t)(bb*HIN + i)*HIN + j)*CIN;
        #pragma unroll
        for (int ci4=0; ci4<CIN/4; ++ci4) {
          float4 v = *(const float4*)(bp + ci4*4);
          if (BN) {
            float4 sc = *(const float4*)(ss + ci4*4);
            float4 sh = *(const float4*)(ss + CIN + ci4*4);
            v.x = fmaxf(0.f, fmaf(v.x, sc.x, sh.x));
            v.y = fmaxf(0.f, fmaf(v.y, sc.y, sh.y));
            v.z = fmaxf(0.f, fmaf(v.z, sc.z, sh.z));
            v.w = fmaxf(0.f, fmaf(v.w, sc.w, sh.w));
          }
          #pragma unroll
          for (int cc=0;cc<COUTT;++cc) {
            float4 w4 = wlds[(tl*COUTT + cc)*(CIN/4) + ci4];
            float a = acc[cc];
            a = fmaf(v.x, w4.x, a);
            a = fmaf(v.y, w4.y, a);
            a = fmaf(v.z, w4.z, a);
            a = fmaf(v.w, w4.w, a);
            acc[cc] = a;
          }
        }
      }
    }
  }
  int m = 2*my + pm, n = 2*nx + pn;
  float* yp = y + ((size_t)(bb*HOUT + m)*HOUT + n)*COUT + c0;
  #pragma unroll
  for (int g=0;g<COUTT/4;++g)
    ((float4*)yp)[g] = make_float4(acc[g*4], acc[g*4+1], acc[g*4+2], acc[g*4+3]);
  // fused stats
  float s[COUTT], q[COUTT];
  #pragma unroll
  for (int cc=0;cc<COUTT;++cc) { s[cc] = acc[cc]; q[cc] = acc[cc]*acc[cc]; }
  #pragma unroll
  for (int off=1; off<64; off<<=1) {
    #pragma unroll
    for (int cc=0;cc<COUTT;++cc) {
      s[cc] += __shfl_xor(s[cc], off);
      q[cc] += __shfl_xor(q[cc], off);
    }
  }
  __shared__ float red[4][2*COUTT];
  int wv = threadIdx.x >> 6, lane = threadIdx.x & 63;
  if (lane == 0) {
    #pragma unroll
    for (int cc=0;cc<COUTT;++cc) { red[wv][cc] = s[cc]; red[wv][COUTT+cc] = q[cc]; }
  }
  __syncthreads();
  if (threadIdx.x < 2*COUTT)
    partials[(size_t)bid*2*COUTT + threadIdx.x] =
      red[0][threadIdx.x]+red[1][threadIdx.x]+red[2][threadIdx.x]+red[3][threadIdx.x];
}

// ---------------- final conv_transpose 16->3 + input BN+ReLU + clip ----------------
__global__ __launch_bounds__(256) void k_convt_final(const float* __restrict__ in,
    const float* __restrict__ w, const float* __restrict__ bias,
    const float* __restrict__ ss, float* __restrict__ out) {
  const int CIN=16, HIN=128, HOUT=256;
  __shared__ float4 wlds[4*3*4];     // [tap][c][ci4]
  int cls = blockIdx.x & 3;
  int pxb = blockIdx.x >> 2;
  int pm = cls >> 1, pn = cls & 1;
  int NTI = (pm == 0) ? 2 : 1;
  int NTJ = (pn == 0) ? 2 : 1;
  int NT = NTI*NTJ;
  if (threadIdx.x < NT*3*4) {
    int e = threadIdx.x;
    int tl = e / 12, rem = e % 12;
    int c = rem / 4, ci4 = rem % 4;
    int ki = pm + 2*(tl / NTJ), kj = pn + 2*(tl % NTJ);
    wlds[e] = *(const float4*)(w + ((size_t)(ki*3+kj)*3 + c)*CIN + ci4*4);
  }
  __syncthreads();
  int t = pxb*256 + threadIdx.x;
  int nx = t % HIN, my = (t/HIN) % HIN, bb = t/(HIN*HIN);
  float a0 = bias[0], a1 = bias[1], a2 = bias[2];
  #pragma unroll 1
  for (int ti=0; ti<NTI; ++ti) {
    #pragma unroll 1
    for (int tj=0; tj<NTJ; ++tj) {
      int tl = ti*NTJ + tj;
      int i = my - ti, j = nx - tj;
      if (i >= 0 && j >= 0) {
        const float* bp = in + ((size_t)(bb*HIN + i)*HIN + j)*CIN;
        #pragma unroll
        for (int ci4=0; ci4<4; ++ci4) {
          float4 v = *(const float4*)(bp + ci4*4);
          float4 sc = *(const float4*)(ss + ci4*4);
          float4 sh = *(const float4*)(ss + CIN + ci4*4);
          v.x = fmaxf(0.f, fmaf(v.x, sc.x, sh.x));
          v.y = fmaxf(0.f, fmaf(v.y, sc.y, sh.y));
          v.z = fmaxf(0.f, fmaf(v.z, sc.z, sh.z));
          v.w = fmaxf(0.f, fmaf(v.w, sc.w, sh.w));
          float4 w0 = wlds[(tl*3 + 0)*4 + ci4];
          float4 w1 = wlds[(tl*3 + 1)*4 + ci4];
          float4 w2 = wlds[(tl*3 + 2)*4 + ci4];
          a0 = fmaf(v.x, w0.x, a0); a0 = fmaf(v.y, w0.y, a0);
          a0 = fmaf(v.z, w0.z, a0); a0 = fmaf(v.w, w0.w, a0);
          a1 = fmaf(v.x, w1.x, a1); a1 = fmaf(v.y, w1.y, a1);
          a1 = fmaf(v.z, w1.z, a1); a1 = fmaf(v.w, w1.w, a1);
          a2 = fmaf(v.x, w2.x, a2); a2 = fmaf(v.y, w2.y, a2);
          a2 = fmaf(v.z, w2.z, a2); a2 = fmaf(v.w, w2.w, a2);
        }
      }
    }
  }
  int m = 2*my + pm, n = 2*nx + pn;
  float* op = out + ((size_t)(bb*HOUT + m)*HOUT + n)*3;
  op[0] = fminf(fmaxf(a0, 1e-12f), 1.0f);
  op[1] = fminf(fmaxf(a1, 1e-12f), 1.0f);
  op[2] = fminf(fmaxf(a2, 1e-12f), 1.0f);
}

extern "C" void kernel_launch(void* const* d_in, const int* in_sizes, int n_in,
                              void* d_out, int out_size, void* d_ws, size_t ws_size,
                              hipStream_t stream) {
  const float* x    = (const float*)d_in[0];
  const float* w_e1 = (const float*)d_in[1];
  const float* b_e1 = (const float*)d_in[2];
  const float* g1   = (const float*)d_in[3];
  const float* be1  = (const float*)d_in[4];
  const float* w_e2 = (const float*)d_in[5];
  const float* b_e2 = (const float*)d_in[6];
  const float* g2   = (const float*)d_in[7];
  const float* be2  = (const float*)d_in[8];
  const float* w_e3 = (const float*)d_in[9];
  const float* b_e3 = (const float*)d_in[10];
  const float* g3   = (const float*)d_in[11];
  const float* be3  = (const float*)d_in[12];
  const float* wmem = (const float*)d_in[13];
  const float* w_d1 = (const float*)d_in[14];
  const float* b_d1 = (const float*)d_in[15];
  const float* gt1  = (const float*)d_in[16];
  const float* bet1 = (const float*)d_in[17];
  const float* w_d2 = (const float*)d_in[18];
  const float* b_d2 = (const float*)d_in[19];
  const float* gt2  = (const float*)d_in[20];
  const float* bet2 = (const float*)d_in[21];
  const float* w_d3 = (const float*)d_in[22];
  const float* b_d3 = (const float*)d_in[23];
  float* out = (float*)d_out;

  float* ws = (float*)d_ws;
  float* A  = ws;                    // 4194304  y1 raw / t2 raw
  float* Cc = A  + 4194304;          // 2097152  y2 raw / t1 raw
  float* E  = Cc + 2097152;          // 1048576  y3 raw
  float* Gz = E  + 1048576;          // 1048576  zhat
  float* ZP = Gz + 1048576;          // 8388608  zhat partials [8][16384][64]
  float* bfbase = ZP + 8388608;
  __bf16* ZH  = (__bf16*)bfbase;                 // 16384*64 each
  __bf16* ZL  = ZH  + 16384*64;
  __bf16* Z2H = ZL  + 16384*64;
  __bf16* Z2L = Z2H + 16384*64;
  __bf16* MH  = Z2L + 16384*64;                  // 2048*64 each
  __bf16* ML  = MH  + 2048*64;
  __bf16* M2H = ML  + 2048*64;
  __bf16* M2L = M2H + 2048*64;
  __bf16* MHT = M2L + 2048*64;                   // 64*2048 each
  __bf16* MLT = MHT + 64*2048;
  float* PT   = (float*)(MLT + 64*2048);         // 131072 BN partials
  float* SS   = PT + 131072;                     // 256
  float* PM   = SS + 256;                        // 131072 partM [8][16384]
  float* PS   = PM + 131072;                     // 131072 partS
  (void)ws_size; (void)in_sizes; (void)n_in; (void)out_size;

  // ---- encoder ----
  k_conv1<<<1024,256,0,stream>>>(x, w_e1, b_e1, A);
  k_stats<16><<<512,256,0,stream>>>(A, 4194304, PT);
  k_finalize2<16,1><<<1,256,0,stream>>>(PT, 512, 1.0/262144.0, g1, be1, SS);
  k_conv_bn<16,32,2,128,64,true><<<512,256,0,stream>>>(A, w_e2, b_e2, SS, Cc, PT);
  k_finalize2<32,2><<<1,256,0,stream>>>(PT, 512, 1.0/65536.0, g2, be2, SS);
  k_conv_bn<32,64,8,64,32,true><<<512,256,0,stream>>>(Cc, w_e3, b_e3, SS, E, PT);
  k_finalize2<64,8><<<1,256,0,stream>>>(PT, 512, 1.0/16384.0, g3, be3, SS);
  // ---- memory addressing (MFMA two-pass; BN3+ReLU fused into prep_z) ----
  k_prep_m<<<128,256,0,stream>>>(wmem, MH, ML, M2H, M2L, MHT, MLT);
  k_prep_z<<<1024,256,0,stream>>>(E, SS, ZH, ZL, Z2H, Z2L);
  k_pass1<<<512,512,0,stream>>>(ZH, ZL, Z2H, Z2L, MH, ML, M2H, M2L, PM, PS);
  k_pass2<<<512,512,0,stream>>>(ZH, ZL, Z2H, Z2L, MH, ML, M2H, M2L, MHT, MLT, PM, PS, ZP);
  k_zcomb<<<4096,256,0,stream>>>(ZP, Gz);
  // ---- decoder ----
  k_convt_bn<64,32,2,32,false><<<512,256,0,stream>>>(Gz, w_d1, b_d1, nullptr, Cc, PT);
  k_finalize2<32,2><<<1,256,0,stream>>>(PT, 512, 1.0/65536.0, gt1, bet1, SS);
  k_convt_bn<32,16,1,64,true><<<1024,256,0,stream>>>(Cc, w_d2, b_d2, SS, A, PT);
  k_finalize2<16,1><<<1,256,0,stream>>>(PT, 1024, 1.0/262144.0, gt2, bet2, SS);
  k_convt_final<<<4096,256,0,stream>>>(A, w_d3, b_d3, SS, out);
}

// Round 5
// 400.899 us; speedup vs baseline: 2.5727x; 1.1451x over previous
//
#include <hip/hip_runtime.h>
#include <math.h>

typedef __bf16 bf16x8 __attribute__((ext_vector_type(8)));
typedef __bf16 bf16x4 __attribute__((ext_vector_type(4)));
typedef float  f32x16 __attribute__((ext_vector_type(16)));

static __device__ __forceinline__ f32x16 zero16() {
  f32x16 v;
  #pragma unroll
  for (int i = 0; i < 16; ++i) v[i] = 0.f;
  return v;
}
static __device__ __forceinline__ unsigned int bfbits(__bf16 b) {
  return (unsigned int)__builtin_bit_cast(unsigned short, b);
}
static __device__ __forceinline__ bf16x8 mk8(unsigned int a, unsigned int b,
                                             unsigned int c, unsigned int d) {
  uint4 t; t.x = a; t.y = b; t.z = c; t.w = d;
  return __builtin_bit_cast(bf16x8, t);
}

// ---------------- conv1: 1x1 stride2, 3->16, fused BN batch-stats partials ----------------
__global__ __launch_bounds__(256) void k_conv1(const float* __restrict__ x,
    const float* __restrict__ w, const float* __restrict__ b, float* __restrict__ y,
    float* __restrict__ partials) {
  int t = blockIdx.x*256 + threadIdx.x;        // 16*128*128 pixels
  int ox = t & 127, oy = (t >> 7) & 127, bb = t >> 14;
  const float* xp = x + ((size_t)((bb*256 + 2*oy)*256 + 2*ox))*3;
  float x0 = xp[0], x1 = xp[1], x2 = xp[2];
  float4 rg[4];
  float4* yp = (float4*)(y + (size_t)t*16);
  #pragma unroll
  for (int g = 0; g < 4; ++g) {
    float4 r;
    r.x = b[g*4+0] + x0*w[g*4+0] + x1*w[16+g*4+0] + x2*w[32+g*4+0];
    r.y = b[g*4+1] + x0*w[g*4+1] + x1*w[16+g*4+1] + x2*w[32+g*4+1];
    r.z = b[g*4+2] + x0*w[g*4+2] + x1*w[16+g*4+2] + x2*w[32+g*4+2];
    r.w = b[g*4+3] + x0*w[g*4+3] + x1*w[16+g*4+3] + x2*w[32+g*4+3];
    rg[g] = r;
    yp[g] = r;
  }
  // fused stats: per-channel sum / sumsq
  float4 s4[4], q4[4];
  #pragma unroll
  for (int g=0; g<4; ++g) {
    s4[g] = rg[g];
    q4[g] = make_float4(rg[g].x*rg[g].x, rg[g].y*rg[g].y, rg[g].z*rg[g].z, rg[g].w*rg[g].w);
  }
  #pragma unroll
  for (int off=1; off<64; off<<=1) {
    #pragma unroll
    for (int g=0; g<4; ++g) {
      s4[g].x += __shfl_xor(s4[g].x, off); s4[g].y += __shfl_xor(s4[g].y, off);
      s4[g].z += __shfl_xor(s4[g].z, off); s4[g].w += __shfl_xor(s4[g].w, off);
      q4[g].x += __shfl_xor(q4[g].x, off); q4[g].y += __shfl_xor(q4[g].y, off);
      q4[g].z += __shfl_xor(q4[g].z, off); q4[g].w += __shfl_xor(q4[g].w, off);
    }
  }
  __shared__ float red[4][32];
  int wv = threadIdx.x >> 6, lane = threadIdx.x & 63;
  if (lane == 0) {
    #pragma unroll
    for (int g=0; g<4; ++g) {
      *(float4*)&red[wv][g*4]      = s4[g];
      *(float4*)&red[wv][16 + g*4] = q4[g];
    }
  }
  __syncthreads();
  if (threadIdx.x < 32)
    partials[(size_t)blockIdx.x*32 + threadIdx.x] =
      red[0][threadIdx.x]+red[1][threadIdx.x]+red[2][threadIdx.x]+red[3][threadIdx.x];
}

// ---------------- finalize: partials([blk][2*COUTT], blk%CSPLIT=chgroup) -> scale/shift ---
template<int C,int CSPLIT>
__global__ __launch_bounds__(256) void k_finalize2(const float* __restrict__ partials, int nblk,
    double inv_n, const float* __restrict__ g, const float* __restrict__ be, float* __restrict__ ss) {
  const int COUTT = C/CSPLIT;
  const int NSTAT = 2*C;
  const int PER = 256/NSTAT;
  __shared__ double red[256];
  int tid = threadIdx.x;
  int st = tid % NSTAT, sub = tid / NSTAT;
  int c = st % C, kind = st / C;
  int cq = c / COUTT, j = c % COUTT;
  int nb = nblk / CSPLIT;
  double acc = 0.0;
  #pragma unroll 4
  for (int i = sub; i < nb; i += PER) {
    int bq = cq + i*CSPLIT;
    acc += (double)partials[(size_t)bq*2*COUTT + kind*COUTT + j];
  }
  red[tid] = acc;
  __syncthreads();
  for (int off = PER>>1; off > 0; off >>= 1) {
    if (sub < off) red[tid] += red[tid + off*NSTAT];
    __syncthreads();
  }
  if (tid < C) {
    double mean = red[tid]*inv_n;
    double var  = red[C+tid]*inv_n - mean*mean;
    float scale = g[tid] * rsqrtf((float)var + 1e-3f);
    float shift = be[tid] - (float)mean*scale;
    ss[tid] = scale; ss[C+tid] = shift;
  }
}

// ---------------- forward 3x3 stride-2 SAME conv, fused input BN+ReLU + fused stats -----
template<int CIN,int COUT,int CSPLIT,int HIN,int HOUT,bool BN>
__global__ __launch_bounds__(256) void k_conv_bn(const float* __restrict__ in,
    const float* __restrict__ w, const float* __restrict__ bias,
    const float* __restrict__ ss, float* __restrict__ y, float* __restrict__ partials) {
  const int COUTT = COUT/CSPLIT;
  const int NW4 = COUTT/4;
  __shared__ float4 wlds[9*CIN*NW4];
  int bid = blockIdx.x;
  int cq  = bid % CSPLIT;
  int pxb = bid / CSPLIT;
  int c0  = cq*COUTT;
  for (int e = threadIdx.x; e < 9*CIN*NW4; e += 256) {
    int r = e / NW4, cg = e % NW4;
    wlds[e] = *(const float4*)(w + (size_t)r*COUT + c0 + cg*4);
  }
  __syncthreads();
  int t0 = pxb*256 + threadIdx.x;
  float4 acc[NW4];
  #pragma unroll
  for (int g=0; g<NW4; ++g) acc[g] = *(const float4*)(bias + c0 + g*4);
  int ox = t0 % HOUT, oy = (t0/HOUT) % HOUT, bb = t0/(HOUT*HOUT);
  #pragma unroll 1
  for (int dy=0; dy<3; ++dy) {
    #pragma unroll 1
    for (int dx=0; dx<3; ++dx) {
      int tap = dy*3+dx;
      int iy = 2*oy + dy, ix = 2*ox + dx;
      if (iy < HIN && ix < HIN) {
        const float* bp = in + ((size_t)(bb*HIN + iy)*HIN + ix)*CIN;
        #pragma unroll
        for (int ci4=0; ci4<CIN/4; ++ci4) {
          float4 v = *(const float4*)(bp + ci4*4);
          if (BN) {
            float4 sc = *(const float4*)(ss + ci4*4);
            float4 sh = *(const float4*)(ss + CIN + ci4*4);
            v.x = fmaxf(0.f, fmaf(v.x, sc.x, sh.x));
            v.y = fmaxf(0.f, fmaf(v.y, sc.y, sh.y));
            v.z = fmaxf(0.f, fmaf(v.z, sc.z, sh.z));
            v.w = fmaxf(0.f, fmaf(v.w, sc.w, sh.w));
          }
          float va[4] = {v.x, v.y, v.z, v.w};
          #pragma unroll
          for (int k=0;k<4;++k) {
            float vk = va[k];
            #pragma unroll
            for (int g=0; g<NW4; ++g) {
              float4 w4 = wlds[(tap*CIN + ci4*4 + k)*NW4 + g];
              acc[g].x = fmaf(vk, w4.x, acc[g].x);
              acc[g].y = fmaf(vk, w4.y, acc[g].y);
              acc[g].z = fmaf(vk, w4.z, acc[g].z);
              acc[g].w = fmaf(vk, w4.w, acc[g].w);
            }
          }
        }
      }
    }
  }
  float4* yp = (float4*)(y + (size_t)t0*COUT + c0);
  #pragma unroll
  for (int g=0;g<NW4;++g) yp[g] = acc[g];
  float4 s4[NW4], q4[NW4];
  #pragma unroll
  for (int g=0; g<NW4; ++g) {
    s4[g] = acc[g];
    q4[g] = make_float4(acc[g].x*acc[g].x, acc[g].y*acc[g].y,
                        acc[g].z*acc[g].z, acc[g].w*acc[g].w);
  }
  #pragma unroll
  for (int off=1; off<64; off<<=1) {
    #pragma unroll
    for (int g=0; g<NW4; ++g) {
      s4[g].x += __shfl_xor(s4[g].x, off); s4[g].y += __shfl_xor(s4[g].y, off);
      s4[g].z += __shfl_xor(s4[g].z, off); s4[g].w += __shfl_xor(s4[g].w, off);
      q4[g].x += __shfl_xor(q4[g].x, off); q4[g].y += __shfl_xor(q4[g].y, off);
      q4[g].z += __shfl_xor(q4[g].z, off); q4[g].w += __shfl_xor(q4[g].w, off);
    }
  }
  __shared__ float red[4][2*COUTT];
  int wv = threadIdx.x >> 6, lane = threadIdx.x & 63;
  if (lane == 0) {
    #pragma unroll
    for (int g=0; g<NW4; ++g) {
      *(float4*)&red[wv][g*4]         = s4[g];
      *(float4*)&red[wv][COUTT + g*4] = q4[g];
    }
  }
  __syncthreads();
  if (threadIdx.x < 2*COUTT)
    partials[(size_t)bid*2*COUTT + threadIdx.x] =
      red[0][threadIdx.x]+red[1][threadIdx.x]+red[2][threadIdx.x]+red[3][threadIdx.x];
}

// ================= memory module (MFMA, flash-style two-pass) =================

__global__ __launch_bounds__(256) void k_prep_z(const float* __restrict__ y3,
    const float* __restrict__ ss,
    __bf16* __restrict__ ZH, __bf16* __restrict__ ZL,
    __bf16* __restrict__ Z2H, __bf16* __restrict__ Z2L) {
  int t = blockIdx.x*256 + threadIdx.x;   // handles 4 elems
  float4 v = ((const float4*)y3)[t];
  int c0 = (t*4) & 63;
  float4 sc = *(const float4*)(ss + c0);
  float4 sh = *(const float4*)(ss + 64 + c0);
  float vv[4];
  vv[0] = fmaxf(0.f, fmaf(v.x, sc.x, sh.x));
  vv[1] = fmaxf(0.f, fmaf(v.y, sc.y, sh.y));
  vv[2] = fmaxf(0.f, fmaf(v.z, sc.z, sh.z));
  vv[3] = fmaxf(0.f, fmaf(v.w, sc.w, sh.w));
  bf16x4 h, l, h2, l2;
  #pragma unroll
  for (int i=0;i<4;++i) {
    float f = vv[i];
    __bf16 hb = (__bf16)f;
    h[i] = hb; l[i] = (__bf16)(f - (float)hb);
    float q = f*f;
    __bf16 qb = (__bf16)q;
    h2[i] = qb; l2[i] = (__bf16)(q - (float)qb);
  }
  ((bf16x4*)ZH)[t] = h;  ((bf16x4*)ZL)[t] = l;
  ((bf16x4*)Z2H)[t] = h2; ((bf16x4*)Z2L)[t] = l2;
}

__global__ __launch_bounds__(256) void k_prep_m(const float* __restrict__ mem,
    __bf16* __restrict__ MH, __bf16* __restrict__ ML,
    __bf16* __restrict__ M2H, __bf16* __restrict__ M2L,
    __bf16* __restrict__ MHT, __bf16* __restrict__ MLT) {
  int t = blockIdx.x*256 + threadIdx.x;   // 2048*16
  int n = t >> 4, c0 = (t & 15)*4;
  float4 v = make_float4(0.f,0.f,0.f,0.f);
  if (n < 2000) v = *(const float4*)(mem + (size_t)n*64 + c0);
  float vv[4] = {v.x, v.y, v.z, v.w};
  bf16x4 h, l, h2, l2;
  #pragma unroll
  for (int i=0;i<4;++i) {
    float f = vv[i];
    __bf16 hb = (__bf16)f;
    h[i] = hb; l[i] = (__bf16)(f - (float)hb);
    float q = f*f;
    __bf16 qb = (__bf16)q;
    h2[i] = qb; l2[i] = (__bf16)(q - (float)qb);
  }
  *(bf16x4*)(MH  + (size_t)n*64 + c0) = h;
  *(bf16x4*)(ML  + (size_t)n*64 + c0) = l;
  *(bf16x4*)(M2H + (size_t)n*64 + c0) = h2;
  *(bf16x4*)(M2L + (size_t)n*64 + c0) = l2;
  #pragma unroll
  for (int i=0;i<4;++i) {
    MHT[(size_t)(c0+i)*2048 + n] = h[i];
    MLT[(size_t)(c0+i)*2048 + n] = l[i];
  }
}

// pass1: scores via MFMA (C rows=n, cols=p) + online softmax partials per 256-n chunk
// 256-thread blocks: pb (128) x chunk (8); each wave owns 32 p-columns
__global__ __launch_bounds__(256) void k_pass1(
    const __bf16* __restrict__ ZH, const __bf16* __restrict__ ZL,
    const __bf16* __restrict__ Z2H, const __bf16* __restrict__ Z2L,
    const __bf16* __restrict__ MH, const __bf16* __restrict__ ML,
    const __bf16* __restrict__ M2H, const __bf16* __restrict__ M2L,
    float* __restrict__ partM, float* __restrict__ partS) {
  int pb = blockIdx.x & 127, chunk = blockIdx.x >> 7;
  int wave = threadIdx.x >> 6, lane = threadIdx.x & 63;
  int p0 = pb*128 + wave*32;
  int col = lane & 31, hi = lane >> 5;
  bf16x8 bzh[4], bzl[4], b2h[4], b2l[4];
  size_t zoff = (size_t)(p0 + col)*64 + hi*8;
  #pragma unroll
  for (int ks=0;ks<4;++ks) {
    bzh[ks] = *(const bf16x8*)(ZH  + zoff + ks*16);
    bzl[ks] = *(const bf16x8*)(ZL  + zoff + ks*16);
    b2h[ks] = *(const bf16x8*)(Z2H + zoff + ks*16);
    b2l[ks] = *(const bf16x8*)(Z2L + zoff + ks*16);
  }
  float m = -3.4e38f, S = 0.f;
  int nbase = chunk*256;
  #pragma unroll 2
  for (int t=0; t<8; ++t) {
    int n0 = nbase + t*32;
    size_t arow = (size_t)(n0 + col)*64 + hi*8;
    f32x16 num = zero16(), den = zero16();
    #pragma unroll
    for (int ks=0;ks<4;++ks) {
      bf16x8 amh = *(const bf16x8*)(MH + arow + ks*16);
      bf16x8 aml = *(const bf16x8*)(ML + arow + ks*16);
      num = __builtin_amdgcn_mfma_f32_32x32x16_bf16(amh, bzh[ks], num, 0,0,0);
      num = __builtin_amdgcn_mfma_f32_32x32x16_bf16(amh, bzl[ks], num, 0,0,0);
      num = __builtin_amdgcn_mfma_f32_32x32x16_bf16(aml, bzh[ks], num, 0,0,0);
      bf16x8 a2h = *(const bf16x8*)(M2H + arow + ks*16);
      bf16x8 a2l = *(const bf16x8*)(M2L + arow + ks*16);
      den = __builtin_amdgcn_mfma_f32_32x32x16_bf16(a2h, b2h[ks], den, 0,0,0);
      den = __builtin_amdgcn_mfma_f32_32x32x16_bf16(a2h, b2l[ks], den, 0,0,0);
      den = __builtin_amdgcn_mfma_f32_32x32x16_bf16(a2l, b2h[ks], den, 0,0,0);
    }
    bool maskt = (n0 + 32 > 2000);
    float sv[16];
    float tmax = -3.4e38f;
    #pragma unroll
    for (int r=0;r<16;++r) {
      float s = (num[r] + 1e-12f) * __builtin_amdgcn_rcpf(den[r] + 1e-12f);
      if (maskt) {
        int nn = n0 + (r&3) + 8*(r>>2) + 4*hi;
        if (nn >= 2000) s = -3.4e38f;
      }
      sv[r] = s;
      tmax = fmaxf(tmax, s);
    }
    float mn = fmaxf(m, tmax);
    float ssum = 0.f;
    #pragma unroll
    for (int r=0;r<16;++r) ssum += __expf(sv[r] - mn);
    S = S*__expf(m - mn) + ssum;
    m = mn;
  }
  float mo = __shfl_xor(m, 32);
  float So = __shfl_xor(S, 32);
  float mf = fmaxf(m, mo);
  float Sf = S*__expf(m - mf) + So*__expf(mo - mf);
  if (lane < 32) {
    int p = p0 + col;
    partM[chunk*16384 + p] = mf;
    partS[chunk*16384 + p] = Sf;
  }
}

// pass2: recompute scores, r = att·[att > 1/N] (exact up to ~1e-12 band), z_hat via MFMA.
// r packed bf16-hi only; in-register transpose via lane-half shuffles.
__global__ __launch_bounds__(256) void k_pass2(
    const __bf16* __restrict__ ZH, const __bf16* __restrict__ ZL,
    const __bf16* __restrict__ Z2H, const __bf16* __restrict__ Z2L,
    const __bf16* __restrict__ MH, const __bf16* __restrict__ ML,
    const __bf16* __restrict__ M2H, const __bf16* __restrict__ M2L,
    const __bf16* __restrict__ MHT, const __bf16* __restrict__ MLT,
    const float* __restrict__ partM, const float* __restrict__ partS,
    float* __restrict__ ZP) {
  int pb = blockIdx.x & 127, chunk = blockIdx.x >> 7;
  int wave = threadIdx.x >> 6, lane = threadIdx.x & 63;
  int p0 = pb*128 + wave*32;
  int col = lane & 31, hi = lane >> 5;
  bf16x8 bzh[4], bzl[4], b2h[4], b2l[4];
  size_t zoff = (size_t)(p0 + col)*64 + hi*8;
  #pragma unroll
  for (int ks=0;ks<4;++ks) {
    bzh[ks] = *(const bf16x8*)(ZH  + zoff + ks*16);
    bzl[ks] = *(const bf16x8*)(ZL  + zoff + ks*16);
    b2h[ks] = *(const bf16x8*)(Z2H + zoff + ks*16);
    b2l[ks] = *(const bf16x8*)(Z2L + zoff + ks*16);
  }
  // combine softmax normalizers: CM = M + ln(S);  att = exp(s - CM)
  int p = p0 + col;
  float pmv[8];
  float Mp = -3.4e38f;
  #pragma unroll
  for (int c=0;c<8;++c) { pmv[c] = partM[c*16384 + p]; Mp = fmaxf(Mp, pmv[c]); }
  float Ssum = 0.f;
  #pragma unroll
  for (int c=0;c<8;++c) Ssum += partS[c*16384 + p] * __expf(pmv[c] - Mp);
  float CM  = Mp + __logf(Ssum);
  float thr = CM - 7.6009025f;     // + ln(1/2000)
  f32x16 za0 = zero16(), za1 = zero16();
  int nbase = chunk*256;
  #pragma unroll 2
  for (int t=0; t<8; ++t) {
    int n0 = nbase + t*32;
    size_t arow = (size_t)(n0 + col)*64 + hi*8;
    f32x16 num = zero16(), den = zero16();
    #pragma unroll
    for (int ks=0;ks<4;++ks) {
      bf16x8 amh = *(const bf16x8*)(MH + arow + ks*16);
      bf16x8 aml = *(const bf16x8*)(ML + arow + ks*16);
      num = __builtin_amdgcn_mfma_f32_32x32x16_bf16(amh, bzh[ks], num, 0,0,0);
      num = __builtin_amdgcn_mfma_f32_32x32x16_bf16(amh, bzl[ks], num, 0,0,0);
      num = __builtin_amdgcn_mfma_f32_32x32x16_bf16(aml, bzh[ks], num, 0,0,0);
      bf16x8 a2h = *(const bf16x8*)(M2H + arow + ks*16);
      bf16x8 a2l = *(const bf16x8*)(M2L + arow + ks*16);
      den = __builtin_amdgcn_mfma_f32_32x32x16_bf16(a2h, b2h[ks], den, 0,0,0);
      den = __builtin_amdgcn_mfma_f32_32x32x16_bf16(a2h, b2l[ks], den, 0,0,0);
      den = __builtin_amdgcn_mfma_f32_32x32x16_bf16(a2l, b2h[ks], den, 0,0,0);
    }
    bool maskt = (n0 + 32 > 2000);
    float rv[16];
    #pragma unroll
    for (int r=0;r<16;++r) {
      float s = (num[r] + 1e-12f) * __builtin_amdgcn_rcpf(den[r] + 1e-12f);
      float att = __expf(s - CM);
      float rr = (s > thr) ? att : 0.f;
      if (maskt) {
        int nn = n0 + (r&3) + 8*(r>>2) + 4*hi;
        if (nn >= 2000) rr = 0.f;
      }
      rv[r] = rr;
    }
    // pack quads to bf16 (hi only): quad qd covers n-local rows 8qd+4hi..+3
    unsigned int qh[8];
    #pragma unroll
    for (int qd=0; qd<4; ++qd) {
      #pragma unroll
      for (int pr=0; pr<2; ++pr) {
        float r0 = rv[qd*4 + pr*2], r1 = rv[qd*4 + pr*2 + 1];
        qh[qd*2+pr] = bfbits((__bf16)r0) | (bfbits((__bf16)r1) << 16);
      }
    }
    unsigned int qhp[8];
    #pragma unroll
    for (int i=0;i<8;++i) qhp[i] = (unsigned int)__shfl_xor((int)qh[i], 32);
    bf16x8 f1h = hi ? mk8(qhp[2],qhp[3],qh[2],qh[3]) : mk8(qh[0],qh[1],qhp[0],qhp[1]);
    bf16x8 f2h = hi ? mk8(qhp[6],qhp[7],qh[6],qh[7]) : mk8(qh[4],qh[5],qhp[4],qhp[5]);
    #pragma unroll
    for (int kh=0; kh<2; ++kh) {
      bf16x8 fh = kh ? f2h : f1h;
      size_t bofs = (size_t)col*2048 + n0 + kh*16 + hi*8;
      bf16x8 bmh0 = *(const bf16x8*)(MHT + bofs);
      bf16x8 bml0 = *(const bf16x8*)(MLT + bofs);
      bf16x8 bmh1 = *(const bf16x8*)(MHT + bofs + (size_t)32*2048);
      bf16x8 bml1 = *(const bf16x8*)(MLT + bofs + (size_t)32*2048);
      za0 = __builtin_amdgcn_mfma_f32_32x32x16_bf16(fh, bmh0, za0, 0,0,0);
      za0 = __builtin_amdgcn_mfma_f32_32x32x16_bf16(fh, bml0, za0, 0,0,0);
      za1 = __builtin_amdgcn_mfma_f32_32x32x16_bf16(fh, bmh1, za1, 0,0,0);
      za1 = __builtin_amdgcn_mfma_f32_32x32x16_bf16(fh, bml1, za1, 0,0,0);
    }
  }
  size_t base = (size_t)chunk << 20;
  #pragma unroll
  for (int r=0;r<16;++r) {
    int prow = (r&3) + 8*(r>>2) + 4*hi;
    size_t o = base + (size_t)(p0 + prow)*64 + col;
    ZP[o]      = za0[r];
    ZP[o + 32] = za1[r];
  }
}

__global__ __launch_bounds__(256) void k_zcomb(const float* __restrict__ ZP,
                                               float* __restrict__ Gz) {
  int t = blockIdx.x*256 + threadIdx.x;   // 1048576
  float a = 0.f;
  #pragma unroll
  for (int c=0;c<8;++c) a += ZP[(size_t)c*1048576 + t];
  Gz[t] = a;
}

// ---------------- conv_transpose 3x3 stride2 SAME, parity-class blocks + fused stats ----
template<int CIN,int COUT,int CSPLIT,int HIN,bool BN>
__global__ __launch_bounds__(256) void k_convt_bn(const float* __restrict__ in,
    const float* __restrict__ w, const float* __restrict__ bias,
    const float* __restrict__ ss, float* __restrict__ y, float* __restrict__ partials) {
  const int COUTT = COUT/CSPLIT;
  const int HOUT = 2*HIN;
  __shared__ float4 wlds[4*COUTT*(CIN/4)];
  int bid = blockIdx.x;
  int cq = bid % CSPLIT; int rest = bid / CSPLIT;
  int cls = rest % 4;    int pxb = rest / 4;
  int pm = cls >> 1, pn = cls & 1;
  int c0 = cq*COUTT;
  int NTI = (pm == 0) ? 2 : 1;
  int NTJ = (pn == 0) ? 2 : 1;
  int NT = NTI*NTJ;
  for (int e = threadIdx.x; e < NT*COUTT*(CIN/4); e += 256) {
    int tl = e / (COUTT*(CIN/4));
    int rem = e % (COUTT*(CIN/4));
    int cc = rem / (CIN/4), ci4 = rem % (CIN/4);
    int ki = pm + 2*(tl / NTJ), kj = pn + 2*(tl % NTJ);
    wlds[e] = *(const float4*)(w + ((size_t)(ki*3+kj)*COUT + c0 + cc)*CIN + ci4*4);
  }
  __syncthreads();
  int t0 = pxb*256 + threadIdx.x;
  float acc[COUTT];
  #pragma unroll
  for (int cc=0;cc<COUTT;++cc) acc[cc] = bias[c0+cc];
  int nx = t0 % HIN, my = (t0/HIN) % HIN, bb = t0/(HIN*HIN);
  #pragma unroll 1
  for (int ti=0; ti<NTI; ++ti) {
    #pragma unroll 1
    for (int tj=0; tj<NTJ; ++tj) {
      int tl = ti*NTJ + tj;
      int i = my - ti, j = nx - tj;
      if (i >= 0 && j >= 0) {
        const float* bp = in + ((size_t)(bb*HIN + i)*HIN + j)*CIN;
        #pragma unroll
        for (int ci4=0; ci4<CIN/4; ++ci4) {
          float4 v = *(const float4*)(bp + ci4*4);
          if (BN) {
            float4 sc = *(const float4*)(ss + ci4*4);
            float4 sh = *(const float4*)(ss + CIN + ci4*4);
            v.x = fmaxf(0.f, fmaf(v.x, sc.x, sh.x));
            v.y = fmaxf(0.f, fmaf(v.y, sc.y, sh.y));
            v.z = fmaxf(0.f, fmaf(v.z, sc.z, sh.z));
            v.w = fmaxf(0.f, fmaf(v.w, sc.w, sh.w));
          }
          #pragma unroll
          for (int cc=0;cc<COUTT;++cc) {
            float4 w4 = wlds[(tl*COUTT + cc)*(CIN/4) + ci4];
            float a = acc[cc];
            a = fmaf(v.x, w4.x, a);
            a = fmaf(v.y, w4.y, a);
            a = fmaf(v.z, w4.z, a);
            a = fmaf(v.w, w4.w, a);
            acc[cc] = a;
          }
        }
      }
    }
  }
  int m = 2*my + pm, n = 2*nx + pn;
  float* yp = y + ((size_t)(bb*HOUT + m)*HOUT + n)*COUT + c0;
  #pragma unroll
  for (int g=0;g<COUTT/4;++g)
    ((float4*)yp)[g] = make_float4(acc[g*4], acc[g*4+1], acc[g*4+2], acc[g*4+3]);
  float s[COUTT], q[COUTT];
  #pragma unroll
  for (int cc=0;cc<COUTT;++cc) { s[cc] = acc[cc]; q[cc] = acc[cc]*acc[cc]; }
  #pragma unroll
  for (int off=1; off<64; off<<=1) {
    #pragma unroll
    for (int cc=0;cc<COUTT;++cc) {
      s[cc] += __shfl_xor(s[cc], off);
      q[cc] += __shfl_xor(q[cc], off);
    }
  }
  __shared__ float red[4][2*COUTT];
  int wv = threadIdx.x >> 6, lane = threadIdx.x & 63;
  if (lane == 0) {
    #pragma unroll
    for (int cc=0;cc<COUTT;++cc) { red[wv][cc] = s[cc]; red[wv][COUTT+cc] = q[cc]; }
  }
  __syncthreads();
  if (threadIdx.x < 2*COUTT)
    partials[(size_t)bid*2*COUTT + threadIdx.x] =
      red[0][threadIdx.x]+red[1][threadIdx.x]+red[2][threadIdx.x]+red[3][threadIdx.x];
}

// ---------------- final conv_transpose 16->3 + input BN+ReLU + clip ----------------
__global__ __launch_bounds__(256) void k_convt_final(const float* __restrict__ in,
    const float* __restrict__ w, const float* __restrict__ bias,
    const float* __restrict__ ss, float* __restrict__ out) {
  const int CIN=16, HIN=128, HOUT=256;
  __shared__ float4 wlds[4*3*4];     // [tap][c][ci4]
  int cls = blockIdx.x & 3;
  int pxb = blockIdx.x >> 2;
  int pm = cls >> 1, pn = cls & 1;
  int NTI = (pm == 0) ? 2 : 1;
  int NTJ = (pn == 0) ? 2 : 1;
  int NT = NTI*NTJ;
  if (threadIdx.x < NT*3*4) {
    int e = threadIdx.x;
    int tl = e / 12, rem = e % 12;
    int c = rem / 4, ci4 = rem % 4;
    int ki = pm + 2*(tl / NTJ), kj = pn + 2*(tl % NTJ);
    wlds[e] = *(const float4*)(w + ((size_t)(ki*3+kj)*3 + c)*CIN + ci4*4);
  }
  __syncthreads();
  int t = pxb*256 + threadIdx.x;
  int nx = t % HIN, my = (t/HIN) % HIN, bb = t/(HIN*HIN);
  float a0 = bias[0], a1 = bias[1], a2 = bias[2];
  #pragma unroll 1
  for (int ti=0; ti<NTI; ++ti) {
    #pragma unroll 1
    for (int tj=0; tj<NTJ; ++tj) {
      int tl = ti*NTJ + tj;
      int i = my - ti, j = nx - tj;
      if (i >= 0 && j >= 0) {
        const float* bp = in + ((size_t)(bb*HIN + i)*HIN + j)*CIN;
        #pragma unroll
        for (int ci4=0; ci4<4; ++ci4) {
          float4 v = *(const float4*)(bp + ci4*4);
          float4 sc = *(const float4*)(ss + ci4*4);
          float4 sh = *(const float4*)(ss + CIN + ci4*4);
          v.x = fmaxf(0.f, fmaf(v.x, sc.x, sh.x));
          v.y = fmaxf(0.f, fmaf(v.y, sc.y, sh.y));
          v.z = fmaxf(0.f, fmaf(v.z, sc.z, sh.z));
          v.w = fmaxf(0.f, fmaf(v.w, sc.w, sh.w));
          float4 w0 = wlds[(tl*3 + 0)*4 + ci4];
          float4 w1 = wlds[(tl*3 + 1)*4 + ci4];
          float4 w2 = wlds[(tl*3 + 2)*4 + ci4];
          a0 = fmaf(v.x, w0.x, a0); a0 = fmaf(v.y, w0.y, a0);
          a0 = fmaf(v.z, w0.z, a0); a0 = fmaf(v.w, w0.w, a0);
          a1 = fmaf(v.x, w1.x, a1); a1 = fmaf(v.y, w1.y, a1);
          a1 = fmaf(v.z, w1.z, a1); a1 = fmaf(v.w, w1.w, a1);
          a2 = fmaf(v.x, w2.x, a2); a2 = fmaf(v.y, w2.y, a2);
          a2 = fmaf(v.z, w2.z, a2); a2 = fmaf(v.w, w2.w, a2);
        }
      }
    }
  }
  int m = 2*my + pm, n = 2*nx + pn;
  float* op = out + ((size_t)(bb*HOUT + m)*HOUT + n)*3;
  op[0] = fminf(fmaxf(a0, 1e-12f), 1.0f);
  op[1] = fminf(fmaxf(a1, 1e-12f), 1.0f);
  op[2] = fminf(fmaxf(a2, 1e-12f), 1.0f);
}

extern "C" void kernel_launch(void* const* d_in, const int* in_sizes, int n_in,
                              void* d_out, int out_size, void* d_ws, size_t ws_size,
                              hipStream_t stream) {
  const float* x    = (const float*)d_in[0];
  const float* w_e1 = (const float*)d_in[1];
  const float* b_e1 = (const float*)d_in[2];
  const float* g1   = (const float*)d_in[3];
  const float* be1  = (const float*)d_in[4];
  const float* w_e2 = (const float*)d_in[5];
  const float* b_e2 = (const float*)d_in[6];
  const float* g2   = (const float*)d_in[7];
  const float* be2  = (const float*)d_in[8];
  const float* w_e3 = (const float*)d_in[9];
  const float* b_e3 = (const float*)d_in[10];
  const float* g3   = (const float*)d_in[11];
  const float* be3  = (const float*)d_in[12];
  const float* wmem = (const float*)d_in[13];
  const float* w_d1 = (const float*)d_in[14];
  const float* b_d1 = (const float*)d_in[15];
  const float* gt1  = (const float*)d_in[16];
  const float* bet1 = (const float*)d_in[17];
  const float* w_d2 = (const float*)d_in[18];
  const float* b_d2 = (const float*)d_in[19];
  const float* gt2  = (const float*)d_in[20];
  const float* bet2 = (const float*)d_in[21];
  const float* w_d3 = (const float*)d_in[22];
  const float* b_d3 = (const float*)d_in[23];
  float* out = (float*)d_out;

  float* ws = (float*)d_ws;
  float* A  = ws;                    // 4194304  y1 raw / t2 raw
  float* Cc = A  + 4194304;          // 2097152  y2 raw / t1 raw
  float* E  = Cc + 2097152;          // 1048576  y3 raw
  float* Gz = E  + 1048576;          // 1048576  zhat
  float* ZP = Gz + 1048576;          // 8388608  zhat partials [8][16384][64]
  float* bfbase = ZP + 8388608;
  __bf16* ZH  = (__bf16*)bfbase;                 // 16384*64 each
  __bf16* ZL  = ZH  + 16384*64;
  __bf16* Z2H = ZL  + 16384*64;
  __bf16* Z2L = Z2H + 16384*64;
  __bf16* MH  = Z2L + 16384*64;                  // 2048*64 each
  __bf16* ML  = MH  + 2048*64;
  __bf16* M2H = ML  + 2048*64;
  __bf16* M2L = M2H + 2048*64;
  __bf16* MHT = M2L + 2048*64;                   // 64*2048 each
  __bf16* MLT = MHT + 64*2048;
  float* PT   = (float*)(MLT + 64*2048);         // 131072 BN partials
  float* SS   = PT + 131072;                     // 256
  float* PM   = SS + 256;                        // 131072 partM [8][16384]
  float* PS   = PM + 131072;                     // 131072 partS
  (void)ws_size; (void)in_sizes; (void)n_in; (void)out_size;

  // ---- encoder ----
  k_conv1<<<1024,256,0,stream>>>(x, w_e1, b_e1, A, PT);
  k_finalize2<16,1><<<1,256,0,stream>>>(PT, 1024, 1.0/262144.0, g1, be1, SS);
  k_conv_bn<16,32,2,128,64,true><<<512,256,0,stream>>>(A, w_e2, b_e2, SS, Cc, PT);
  k_finalize2<32,2><<<1,256,0,stream>>>(PT, 512, 1.0/65536.0, g2, be2, SS);
  k_conv_bn<32,64,8,64,32,true><<<512,256,0,stream>>>(Cc, w_e3, b_e3, SS, E, PT);
  k_finalize2<64,8><<<1,256,0,stream>>>(PT, 512, 1.0/16384.0, g3, be3, SS);
  // ---- memory addressing (MFMA two-pass; BN3+ReLU fused into prep_z) ----
  k_prep_m<<<128,256,0,stream>>>(wmem, MH, ML, M2H, M2L, MHT, MLT);
  k_prep_z<<<1024,256,0,stream>>>(E, SS, ZH, ZL, Z2H, Z2L);
  k_pass1<<<1024,256,0,stream>>>(ZH, ZL, Z2H, Z2L, MH, ML, M2H, M2L, PM, PS);
  k_pass2<<<1024,256,0,stream>>>(ZH, ZL, Z2H, Z2L, MH, ML, M2H, M2L, MHT, MLT, PM, PS, ZP);
  k_zcomb<<<4096,256,0,stream>>>(ZP, Gz);
  // ---- decoder ----
  k_convt_bn<64,32,2,32,false><<<512,256,0,stream>>>(Gz, w_d1, b_d1, nullptr, Cc, PT);
  k_finalize2<32,2><<<1,256,0,stream>>>(PT, 512, 1.0/65536.0, gt1, bet1, SS);
  k_convt_bn<32,16,1,64,true><<<1024,256,0,stream>>>(Cc, w_d2, b_d2, SS, A, PT);
  k_finalize2<16,1><<<1,256,0,stream>>>(PT, 1024, 1.0/262144.0, gt2, bet2, SS);
  k_convt_final<<<4096,256,0,stream>>>(A, w_d3, b_d3, SS, out);
}